// Round 10
// baseline (488.891 us; speedup 1.0000x reference)
//
#include <hip/hip_runtime.h>

#define PI_F 3.14159265358979f
#define CAP 256

__device__ __forceinline__ float2 cadd(float2 a, float2 b){ return make_float2(a.x+b.x, a.y+b.y); }
__device__ __forceinline__ float2 csub(float2 a, float2 b){ return make_float2(a.x-b.x, a.y-b.y); }
__device__ __forceinline__ float2 cmul(float2 a, float2 b){ return make_float2(a.x*b.x - a.y*b.y, a.x*b.y + a.y*b.x); }

// XOR swizzle on complex index for FFT ping-pong buffers
#define PH(i) ((i) ^ ((((unsigned)(i))>>5)&7))

// COMPILER-ONLY fence: LDS pipe is in-order per wave (buffers are wave-private),
// so cross-lane visibility needs no hardware drain — only a reorder barrier.
__device__ __forceinline__ void cfence() {
    asm volatile("" ::: "memory");
}

// ---------------- kernel A: per-row softmax stats (max, 1/sumexp) ----------------
__global__ __launch_bounds__(256) void ksoft(const float* __restrict__ sel,
                                             float* __restrict__ rowmax,
                                             float* __restrict__ rowinv)
{
    const int row = blockIdx.x;
    const int tid = threadIdx.x;
    const float4* p4 = (const float4*)(sel + (size_t)row * 4096);
    float4 v[4];
    float mx = -3.0e38f;
#pragma unroll
    for (int i = 0; i < 4; ++i) {
        v[i] = p4[tid + (i<<8)];
        mx = fmaxf(mx, fmaxf(fmaxf(v[i].x, v[i].y), fmaxf(v[i].z, v[i].w)));
    }
#pragma unroll
    for (int o = 32; o >= 1; o >>= 1) mx = fmaxf(mx, __shfl_xor(mx, o));
    __shared__ float red[8];
    const int wv = tid >> 6;
    if ((tid & 63) == 0) red[wv] = mx;
    __syncthreads();
    mx = fmaxf(fmaxf(red[0], red[1]), fmaxf(red[2], red[3]));
    float s = 0.0f;
#pragma unroll
    for (int i = 0; i < 4; ++i) {
        s += __expf(v[i].x - mx) + __expf(v[i].y - mx) + __expf(v[i].z - mx) + __expf(v[i].w - mx);
    }
#pragma unroll
    for (int o = 32; o >= 1; o >>= 1) s += __shfl_xor(s, o);
    if ((tid & 63) == 0) red[4 + wv] = s;
    __syncthreads();
    if (tid == 0) {
        rowmax[row] = mx;
        rowinv[row] = 1.0f / (red[4] + red[5] + red[6] + red[7]);
    }
}

// ---------------- kernel A2: W^T[k][m] = softmax weight, tiled transpose ----------------
__global__ __launch_bounds__(256) void kT(const float* __restrict__ sel,
                                          const float* __restrict__ rowmax,
                                          const float* __restrict__ rowinv,
                                          float* __restrict__ WT)
{
    __shared__ float tile[64][65];
    __shared__ float smx[64], sinv[64];
    const int t = threadIdx.x;
    const int k0 = blockIdx.x * 64;
    const int m0 = blockIdx.y * 64;

    if (t < 64) { smx[t] = rowmax[m0 + t]; sinv[t] = rowinv[m0 + t]; }
    __syncthreads();

    const int m_l = t >> 4;            // 0..15
    const int k_l4 = (t & 15) << 2;    // 0,4,..,60
#pragma unroll
    for (int i = 0; i < 4; ++i) {
        const int ml = m_l + (i << 4);
        const float mxv = smx[ml], invv = sinv[ml];
        float4 v = *(const float4*)(sel + (size_t)(m0 + ml) * 4096 + k0 + k_l4);
        tile[k_l4 + 0][ml] = __expf(v.x - mxv) * invv;
        tile[k_l4 + 1][ml] = __expf(v.y - mxv) * invv;
        tile[k_l4 + 2][ml] = __expf(v.z - mxv) * invv;
        tile[k_l4 + 3][ml] = __expf(v.w - mxv) * invv;
    }
    __syncthreads();

    const int k_l = t >> 2;            // 0..63
    const int mb = (t & 3) << 2;       // 0,4,8,12
#pragma unroll
    for (int i = 0; i < 4; ++i) {
        const int ml = mb + (i << 4);
        float4 w = make_float4(tile[k_l][ml], tile[k_l][ml+1], tile[k_l][ml+2], tile[k_l][ml+3]);
        *(float4*)(WT + (size_t)(k0 + k_l) * 1024 + m0 + ml) = w;
    }
}

// ---------------- kernel B: build per-column nonzero lists of items (deterministic) -----
__global__ __launch_bounds__(256) void kfill(const float* __restrict__ items,
                                             int* __restrict__ kidx,
                                             float* __restrict__ kval,
                                             int* __restrict__ ncol)
{
    const int c = blockIdx.x;
    const int t = threadIdx.x;
    const int wv = t >> 6;
    const int lane = t & 63;
    __shared__ int wcnt[4];

    const int kc0 = wv << 10;
    float vv[16];
    int cnt = 0;
#pragma unroll
    for (int it = 0; it < 16; ++it) {
        const int k = kc0 + (it << 6) + lane;
        const float v = items[(size_t)k * 514 + c];
        vv[it] = v;
        unsigned long long mb = __ballot(v != 0.0f);
        cnt += __popcll(mb);
    }
    if (lane == 0) wcnt[wv] = cnt;
    __syncthreads();

    int base = 0;
#pragma unroll
    for (int q = 0; q < 4; ++q) if (q < wv) base += wcnt[q];

    const unsigned long long ltmask = (lane == 63) ? 0x7fffffffffffffffull
                                                   : ((1ull << lane) - 1ull);
#pragma unroll
    for (int it = 0; it < 16; ++it) {
        const float v = vv[it];
        const bool nz = (v != 0.0f);
        unsigned long long mb = __ballot(nz);
        if (nz) {
            const int slot = base + __popcll(mb & ltmask);
            if (slot < CAP) {
                kidx[c * CAP + slot] = kc0 + (it << 6) + lane;
                kval[c * CAP + slot] = v;
            }
        }
        base += __popcll(mb);
    }
    if (t == 0) ncol[c] = wcnt[0] + wcnt[1] + wcnt[2] + wcnt[3];
}

// ---------------- kernel B2: sparse matmul + transform -> P planes ----------------
__global__ __launch_bounds__(256) void kspmm(const float* __restrict__ WT,
                                             const int* __restrict__ kidx,
                                             const float* __restrict__ kval,
                                             const int* __restrict__ ncol,
                                             float* __restrict__ P)
{
    const int c = blockIdx.x;
    const int m = (blockIdx.y << 8) + threadIdx.x;
    const int nn = min(ncol[c], CAP);
    const int* ki = kidx + c * CAP;
    const float* kv = kval + c * CAP;

    float acc = 0.0f;
    int i = 0;
    for (; i + 4 <= nn; i += 4) {
        const int k0 = ki[i], k1 = ki[i+1], k2 = ki[i+2], k3 = ki[i+3];
        const float v0 = kv[i], v1 = kv[i+1], v2 = kv[i+2], v3 = kv[i+3];
        const float w0 = WT[(size_t)k0 * 1024 + m];
        const float w1 = WT[(size_t)k1 * 1024 + m];
        const float w2 = WT[(size_t)k2 * 1024 + m];
        const float w3 = WT[(size_t)k3 * 1024 + m];
        acc = fmaf(v0, w0, acc);
        acc = fmaf(v1, w1, acc);
        acc = fmaf(v2, w2, acc);
        acc = fmaf(v3, w3, acc);
    }
    for (; i < nn; ++i) {
        acc = fmaf(kv[i], WT[(size_t)ki[i] * 1024 + m], acc);
    }

    float* Lp = P;
    float* Mp = P + 1024*257;
    float* Cp = P + 2*1024*257;
    float* Sp = P + 3*1024*257;
    const float x = acc;
    if (c < 257) {
        float mm = 0.9999f / (1.0f + __expf(-x));
        const int idx = m * 257 + c;
        Lp[idx] = __log2f(mm);
        Mp[idx] = mm;
    } else {
        const int idx = m * 257 + (c - 257);
        float e2 = __expf(2.0f * x);
        float th = (e2 - 1.0f) / (e2 + 1.0f);
        float ph = PI_F * th;
        float sn, cs;
        __sincosf(ph, &sn, &cs);
        Cp[idx] = cs;
        Sp[idx] = sn;
    }
}

// ---------------- kernel C: spectral + IFFT, wave-private LDS, compiler fences only ----------
// Register diet + __launch_bounds__(256,8): target VGPR <= 64 for 2x wave occupancy.
__global__ __launch_bounds__(256, 8) void kres(const float* __restrict__ P, float* __restrict__ out)
{
    const int tid = threadIdx.x;
    const int lane = tid & 63;
    const int wv = tid >> 6;
    const int item = blockIdx.x >> 3;
    const int jg = blockIdx.x & 7;

    __shared__ float2 bufA_s[4][257];
    __shared__ float2 bufB_s[4][257];
    float2* bufA = bufA_s[wv];
    float2* bufB = bufB_s[wv];

    // Stage twiddles: store w1,w2 per stage; w3 derived at use (w3 = w1*w2).
    const float A256 = 6.283185307179586f / 256.0f;
    float2 s0w1, s0w2, s1w1, s1w2, s2w1, s2w2;
    {
        float s, c;
        const int p1 = (lane >> 2) << 2;
        const int p2 = (lane >> 4) << 4;
        __sincosf(A256 * (float)lane,     &s, &c); s0w1 = make_float2(c, s);
        __sincosf(A256 * (float)(2*lane), &s, &c); s0w2 = make_float2(c, s);
        __sincosf(A256 * (float)p1,       &s, &c); s1w1 = make_float2(c, s);
        __sincosf(A256 * (float)(2*p1),   &s, &c); s1w2 = make_float2(c, s);
        __sincosf(A256 * (float)p2,       &s, &c); s2w1 = make_float2(c, s);
        __sincosf(A256 * (float)(2*p2),   &s, &c); s2w2 = make_float2(c, s);
    }
    // Packing twiddle base: zw0 = e^{+2pi i lane/512}; zwr[r] = zw0 * e^{i pi r/4} derived inline.
    float2 zw0;
    {
        float s, c;
        __sincosf((6.283185307179586f/512.0f) * (float)lane, &s, &c);
        zw0 = make_float2(c, s);
    }

    const float* Lp = P;
    const float* Mp = P + 1024*257;
    const float* Cp = P + 2*1024*257;
    const float* Sp = P + 3*1024*257;
    const int pb = item * 257;
    const int j0 = jg*16 + wv;

    float mg[4], cf[4], sf[4], p[4], m4[4];
#pragma unroll
    for (int r = 0; r < 4; ++r) {
        int c = lane + (r<<6);
        float lv = Lp[pb + c];          // consumed immediately; not persistent
        mg[r] = Mp[pb + c];
        cf[r] = Cp[pb + c];
        sf[r] = Sp[pb + c];
        float m2 = mg[r] * mg[r];
        m4[r] = m2 * m2;
        p[r] = exp2f((float)j0 * lv);
    }
    const float m6 = Mp[pb + 256];
    const float c6 = Cp[pb + 256];
    float p6 = exp2f((float)j0 * Lp[pb + 256]);
    const float m6_2 = m6 * m6;
    const float m6_4 = m6_2 * m6_2;

    float2* outbase = (float2*)out + (size_t)item * 16384;

    for (int t = 0; t < 4; ++t) {
        const int j = j0 + (t<<2);
        const float gf = (j > 0) ? 1.0f : 0.0f;
        const float g = (lane & 1) ? -gf : gf;

        // ---- phase 1: S (regs) and V -> bufB
        float2 S[4];
#pragma unroll
        for (int r = 0; r < 4; ++r) {
            int c = lane + (r<<6);
            float pc = p[r] * cf[r], ps = p[r] * sf[r];
            float mpc = mg[r] * pc, mps = mg[r] * ps;
            float2 Sv = make_float2(fmaf(g, pc, mpc), fmaf(g, ps, mps));
            float2 Vv = make_float2(fmaf(-g, pc, mpc), fmaf(-g, ps, mps));
            if (c == 0) { Sv.y = 0.0f; Vv.y = 0.0f; }
            S[r] = Sv;
            bufB[c] = Vv;
        }
        const float S6 = p6 * (m6 + gf) * c6;
        const float V6 = p6 * (m6 - gf) * c6;
        if (lane == 0) bufB[256] = make_float2(V6, 0.0f);
        cfence();

        // ---- phase 2: H[c] = 0.5 S - 0.25 (V[c-1]+V[c+1]) -> bufA
#pragma unroll
        for (int r = 0; r < 4; ++r) {
            int c = lane + (r<<6);
            float2 Vm;
            if (c == 0) { float2 v1 = bufB[1]; Vm = make_float2(v1.x, -v1.y); }
            else Vm = bufB[c-1];
            float2 Vp = bufB[c+1];
            bufA[c] = make_float2(0.5f*S[r].x - 0.25f*(Vm.x + Vp.x),
                                  0.5f*S[r].y - 0.25f*(Vm.y + Vp.y));
        }
        if (lane == 0) {
            float2 v255 = bufB[255];
            bufA[256] = make_float2(0.5f*S6 - 0.5f*v255.x, 0.0f);
        }
        cfence();

        // ---- phase 3: half-size packing -> Z (regs); zwr derived from zw0
        float2 Z[4];
#pragma unroll
        for (int r = 0; r < 4; ++r) {
            int k = lane + (r<<6);
            float2 Hk = bufA[k];
            float2 Hm = bufA[256-k];
            const float C45 = 0.70710678118654752f;
            float2 w;
            if      (r == 0) w = zw0;
            else if (r == 1) w = make_float2(C45*(zw0.x - zw0.y),  C45*(zw0.x + zw0.y));
            else if (r == 2) w = make_float2(-zw0.y, zw0.x);
            else             w = make_float2(-C45*(zw0.x + zw0.y), C45*(zw0.x - zw0.y));
            float Ar = Hk.x + Hm.x, Ai = Hk.y - Hm.y;
            float Br = Hk.x - Hm.x, Bi = Hk.y + Hm.y;
            float iwr = -w.y*Br - w.x*Bi;
            float iwi =  w.x*Br - w.y*Bi;
            Z[r] = make_float2((Ar + iwr)*(1.0f/512.0f), (Ai + iwi)*(1.0f/512.0f));
        }
        cfence();

        // ---- FFT stage 0 (lane-local) -> bufB
        {
            float2 apc = cadd(Z[0], Z[2]), amc = csub(Z[0], Z[2]);
            float2 bpd = cadd(Z[1], Z[3]);
            float2 jb = make_float2(Z[3].y - Z[1].y, Z[1].x - Z[3].x);
            float2 w3 = cmul(s0w1, s0w2);
            const int base = lane << 2;
            bufB[PH(base + 0)] = cadd(apc, bpd);
            bufB[PH(base + 1)] = cmul(s0w1, cadd(amc, jb));
            bufB[PH(base + 2)] = cmul(s0w2, csub(apc, bpd));
            bufB[PH(base + 3)] = cmul(w3,   csub(amc, jb));
        }
        cfence();

        // ---- FFT stage 1 (s=4): bufB -> bufA
        {
            float2 A = bufB[PH(lane)];
            float2 B = bufB[PH(lane + 64)];
            float2 C = bufB[PH(lane + 128)];
            float2 D = bufB[PH(lane + 192)];
            float2 apc = cadd(A, C), amc = csub(A, C);
            float2 bpd = cadd(B, D);
            float2 jb = make_float2(D.y - B.y, B.x - D.x);
            float2 w3 = cmul(s1w1, s1w2);
            const int ob = (lane & 3) + ((lane >> 2) << 4);
            bufA[PH(ob)]      = cadd(apc, bpd);
            bufA[PH(ob + 4)]  = cmul(s1w1, cadd(amc, jb));
            bufA[PH(ob + 8)]  = cmul(s1w2, csub(apc, bpd));
            bufA[PH(ob + 12)] = cmul(w3,   csub(amc, jb));
        }
        cfence();

        // ---- FFT stage 2 (s=16): bufA -> bufB
        {
            float2 A = bufA[PH(lane)];
            float2 B = bufA[PH(lane + 64)];
            float2 C = bufA[PH(lane + 128)];
            float2 D = bufA[PH(lane + 192)];
            float2 apc = cadd(A, C), amc = csub(A, C);
            float2 bpd = cadd(B, D);
            float2 jb = make_float2(D.y - B.y, B.x - D.x);
            float2 w3 = cmul(s2w1, s2w2);
            const int ob = (lane & 15) + ((lane >> 4) << 6);
            bufB[PH(ob)]      = cadd(apc, bpd);
            bufB[PH(ob + 16)] = cmul(s2w1, cadd(amc, jb));
            bufB[PH(ob + 32)] = cmul(s2w2, csub(apc, bpd));
            bufB[PH(ob + 48)] = cmul(w3,   csub(amc, jb));
        }
        cfence();

        // ---- stage 3 fused (twiddles=1, lower half only) + store
        {
            float2 A = bufB[PH(lane)];
            float2 B = bufB[PH(lane + 64)];
            float2 C = bufB[PH(lane + 128)];
            float2 D = bufB[PH(lane + 192)];
            float2 apc = cadd(A, C), amc = csub(A, C);
            float2 bpd = cadd(B, D);
            float2 jb = make_float2(D.y - B.y, B.x - D.x);
            float2 y0 = cadd(apc, bpd);
            float2 y1 = cadd(amc, jb);
            float2* o2 = outbase + (j << 7);
            o2[lane] = y0;
            o2[lane + 64] = y1;
        }
        cfence();

#pragma unroll
        for (int r = 0; r < 4; ++r) p[r] *= m4[r];
        p6 *= m6_4;
    }
}

extern "C" void kernel_launch(void* const* d_in, const int* in_sizes, int n_in,
                              void* d_out, int out_size, void* d_ws, size_t ws_size,
                              hipStream_t stream)
{
    const float* sel   = (const float*)d_in[0];   // (8,32,4,4096) f32 -> [1024][4096]
    const float* items = (const float*)d_in[1];   // (4096,514) f32
    float* out = (float*)d_out;                   // [1024][32768] f32
    float* ws  = (float*)d_ws;

    // Scratch in d_out (all dead before kres rewrites out):
    float* WT     = out;                          // 4096*1024 = 4,194,304 f
    float* rowmax = out + 4194304;                // 1024
    float* rowinv = out + 4195328;                // 1024
    int*   ncol   = (int*)(out + 4196352);        // 514
    int*   kidx   = (int*)(out + 4196866);        // 514*CAP
    float* kval   = (float*)(out + 4196866 + 514*CAP);
    float* P      = ws;                           // 4*1024*257 floats

    ksoft<<<1024, 256, 0, stream>>>(sel, rowmax, rowinv);
    kT<<<dim3(64, 16), 256, 0, stream>>>(sel, rowmax, rowinv, WT);
    kfill<<<514, 256, 0, stream>>>(items, kidx, kval, ncol);
    kspmm<<<dim3(514, 4), 256, 0, stream>>>(WT, kidx, kval, ncol, P);
    kres<<<8192, 256, 0, stream>>>(P, out);
}

// Round 11
// 466.746 us; speedup vs baseline: 1.0474x; 1.0474x over previous
//
#include <hip/hip_runtime.h>

#define PI_F 3.14159265358979f
#define CAP 256

__device__ __forceinline__ float2 cadd(float2 a, float2 b){ return make_float2(a.x+b.x, a.y+b.y); }
__device__ __forceinline__ float2 csub(float2 a, float2 b){ return make_float2(a.x-b.x, a.y-b.y); }
__device__ __forceinline__ float2 cmul(float2 a, float2 b){ return make_float2(a.x*b.x - a.y*b.y, a.x*b.y + a.y*b.x); }

// XOR swizzle on complex index for FFT ping-pong buffers
#define PH(i) ((i) ^ ((((unsigned)(i))>>5)&7))

// COMPILER-ONLY fence: LDS pipe is in-order per wave (buffers are wave-private),
// so cross-lane visibility needs no hardware drain — only a reorder barrier.
__device__ __forceinline__ void cfence() {
    asm volatile("" ::: "memory");
}

// ---------------- kernel A: per-row softmax stats (max, 1/sumexp) ----------------
__global__ __launch_bounds__(256) void ksoft(const float* __restrict__ sel,
                                             float* __restrict__ rowmax,
                                             float* __restrict__ rowinv)
{
    const int row = blockIdx.x;
    const int tid = threadIdx.x;
    const float4* p4 = (const float4*)(sel + (size_t)row * 4096);
    float4 v[4];
    float mx = -3.0e38f;
#pragma unroll
    for (int i = 0; i < 4; ++i) {
        v[i] = p4[tid + (i<<8)];
        mx = fmaxf(mx, fmaxf(fmaxf(v[i].x, v[i].y), fmaxf(v[i].z, v[i].w)));
    }
#pragma unroll
    for (int o = 32; o >= 1; o >>= 1) mx = fmaxf(mx, __shfl_xor(mx, o));
    __shared__ float red[8];
    const int wv = tid >> 6;
    if ((tid & 63) == 0) red[wv] = mx;
    __syncthreads();
    mx = fmaxf(fmaxf(red[0], red[1]), fmaxf(red[2], red[3]));
    float s = 0.0f;
#pragma unroll
    for (int i = 0; i < 4; ++i) {
        s += __expf(v[i].x - mx) + __expf(v[i].y - mx) + __expf(v[i].z - mx) + __expf(v[i].w - mx);
    }
#pragma unroll
    for (int o = 32; o >= 1; o >>= 1) s += __shfl_xor(s, o);
    if ((tid & 63) == 0) red[4 + wv] = s;
    __syncthreads();
    if (tid == 0) {
        rowmax[row] = mx;
        rowinv[row] = 1.0f / (red[4] + red[5] + red[6] + red[7]);
    }
}

// ---------------- kernel A2: W^T[k][m] = softmax weight, tiled transpose ----------------
__global__ __launch_bounds__(256) void kT(const float* __restrict__ sel,
                                          const float* __restrict__ rowmax,
                                          const float* __restrict__ rowinv,
                                          float* __restrict__ WT)
{
    __shared__ float tile[64][65];
    __shared__ float smx[64], sinv[64];
    const int t = threadIdx.x;
    const int k0 = blockIdx.x * 64;
    const int m0 = blockIdx.y * 64;

    if (t < 64) { smx[t] = rowmax[m0 + t]; sinv[t] = rowinv[m0 + t]; }
    __syncthreads();

    const int m_l = t >> 4;            // 0..15
    const int k_l4 = (t & 15) << 2;    // 0,4,..,60
#pragma unroll
    for (int i = 0; i < 4; ++i) {
        const int ml = m_l + (i << 4);
        const float mxv = smx[ml], invv = sinv[ml];
        float4 v = *(const float4*)(sel + (size_t)(m0 + ml) * 4096 + k0 + k_l4);
        tile[k_l4 + 0][ml] = __expf(v.x - mxv) * invv;
        tile[k_l4 + 1][ml] = __expf(v.y - mxv) * invv;
        tile[k_l4 + 2][ml] = __expf(v.z - mxv) * invv;
        tile[k_l4 + 3][ml] = __expf(v.w - mxv) * invv;
    }
    __syncthreads();

    const int k_l = t >> 2;            // 0..63
    const int mb = (t & 3) << 2;       // 0,4,8,12
#pragma unroll
    for (int i = 0; i < 4; ++i) {
        const int ml = mb + (i << 4);
        float4 w = make_float4(tile[k_l][ml], tile[k_l][ml+1], tile[k_l][ml+2], tile[k_l][ml+3]);
        *(float4*)(WT + (size_t)(k0 + k_l) * 1024 + m0 + ml) = w;
    }
}

// ---------------- kernel B: build per-column nonzero lists of items (deterministic) -----
__global__ __launch_bounds__(256) void kfill(const float* __restrict__ items,
                                             int* __restrict__ kidx,
                                             float* __restrict__ kval,
                                             int* __restrict__ ncol)
{
    const int c = blockIdx.x;
    const int t = threadIdx.x;
    const int wv = t >> 6;
    const int lane = t & 63;
    __shared__ int wcnt[4];

    const int kc0 = wv << 10;
    float vv[16];
    int cnt = 0;
#pragma unroll
    for (int it = 0; it < 16; ++it) {
        const int k = kc0 + (it << 6) + lane;
        const float v = items[(size_t)k * 514 + c];
        vv[it] = v;
        unsigned long long mb = __ballot(v != 0.0f);
        cnt += __popcll(mb);
    }
    if (lane == 0) wcnt[wv] = cnt;
    __syncthreads();

    int base = 0;
#pragma unroll
    for (int q = 0; q < 4; ++q) if (q < wv) base += wcnt[q];

    const unsigned long long ltmask = (lane == 63) ? 0x7fffffffffffffffull
                                                   : ((1ull << lane) - 1ull);
#pragma unroll
    for (int it = 0; it < 16; ++it) {
        const float v = vv[it];
        const bool nz = (v != 0.0f);
        unsigned long long mb = __ballot(nz);
        if (nz) {
            const int slot = base + __popcll(mb & ltmask);
            if (slot < CAP) {
                kidx[c * CAP + slot] = kc0 + (it << 6) + lane;
                kval[c * CAP + slot] = v;
            }
        }
        base += __popcll(mb);
    }
    if (t == 0) ncol[c] = wcnt[0] + wcnt[1] + wcnt[2] + wcnt[3];
}

// ---------------- kernel B2: sparse matmul + transform -> P planes ----------------
__global__ __launch_bounds__(256) void kspmm(const float* __restrict__ WT,
                                             const int* __restrict__ kidx,
                                             const float* __restrict__ kval,
                                             const int* __restrict__ ncol,
                                             float* __restrict__ P)
{
    const int c = blockIdx.x;
    const int m = (blockIdx.y << 8) + threadIdx.x;
    const int nn = min(ncol[c], CAP);
    const int* ki = kidx + c * CAP;
    const float* kv = kval + c * CAP;

    float acc = 0.0f;
    int i = 0;
    for (; i + 4 <= nn; i += 4) {
        const int k0 = ki[i], k1 = ki[i+1], k2 = ki[i+2], k3 = ki[i+3];
        const float v0 = kv[i], v1 = kv[i+1], v2 = kv[i+2], v3 = kv[i+3];
        const float w0 = WT[(size_t)k0 * 1024 + m];
        const float w1 = WT[(size_t)k1 * 1024 + m];
        const float w2 = WT[(size_t)k2 * 1024 + m];
        const float w3 = WT[(size_t)k3 * 1024 + m];
        acc = fmaf(v0, w0, acc);
        acc = fmaf(v1, w1, acc);
        acc = fmaf(v2, w2, acc);
        acc = fmaf(v3, w3, acc);
    }
    for (; i < nn; ++i) {
        acc = fmaf(kv[i], WT[(size_t)ki[i] * 1024 + m], acc);
    }

    float* Lp = P;
    float* Mp = P + 1024*257;
    float* Cp = P + 2*1024*257;
    float* Sp = P + 3*1024*257;
    const float x = acc;
    if (c < 257) {
        float mm = 0.9999f / (1.0f + __expf(-x));
        const int idx = m * 257 + c;
        Lp[idx] = __log2f(mm);
        Mp[idx] = mm;
    } else {
        const int idx = m * 257 + (c - 257);
        float e2 = __expf(2.0f * x);
        float th = (e2 - 1.0f) / (e2 + 1.0f);
        float ph = PI_F * th;
        float sn, cs;
        __sincosf(ph, &sn, &cs);
        Cp[idx] = cs;
        Sp[idx] = sn;
    }
}

// ---------------- kernel C: spectral + IFFT, wave-private LDS, compiler fences only ----------
// Deep register diet (~50 live): p folded into trig (pcf,psf), one stored twiddle per
// FFT stage (w2=w1^2, w3=w1*w2 derived), bin-256 folded. Target: VGPR<=64, 8 waves/SIMD.
__global__ __launch_bounds__(256, 8) void kres(const float* __restrict__ P, float* __restrict__ out)
{
    const int tid = threadIdx.x;
    const int lane = tid & 63;
    const int wv = tid >> 6;
    const int item = blockIdx.x >> 3;
    const int jg = blockIdx.x & 7;

    __shared__ float2 bufA_s[4][257];
    __shared__ float2 bufB_s[4][257];
    float2* bufA = bufA_s[wv];
    float2* bufB = bufB_s[wv];

    // One stored twiddle per FFT stage; w2/w3 derived at use.
    const float A256 = 6.283185307179586f / 256.0f;
    float2 s0w1, s1w1, s2w1, zw0;
    {
        float s, c;
        __sincosf(A256 * (float)lane,                  &s, &c); s0w1 = make_float2(c, s);
        __sincosf(A256 * (float)((lane >> 2) << 2),    &s, &c); s1w1 = make_float2(c, s);
        __sincosf(A256 * (float)((lane >> 4) << 4),    &s, &c); s2w1 = make_float2(c, s);
        __sincosf((6.283185307179586f/512.0f) * (float)lane, &s, &c); zw0 = make_float2(c, s);
    }

    const float* Lp = P;
    const float* Mp = P + 1024*257;
    const float* Cp = P + 2*1024*257;
    const float* Sp = P + 3*1024*257;
    const int pb = item * 257;
    const int j0 = jg*16 + wv;

    // Persistent per-bin state: pcf = m^j * cos, psf = m^j * sin, mg = m, m4 = m^4.
    float pcf[4], psf[4], mg[4], m4[4];
#pragma unroll
    for (int r = 0; r < 4; ++r) {
        int c = lane + (r<<6);
        float lv = Lp[pb + c];
        mg[r] = Mp[pb + c];
        float m2 = mg[r] * mg[r];
        m4[r] = m2 * m2;
        float p0 = exp2f((float)j0 * lv);
        pcf[r] = p0 * Cp[pb + c];
        psf[r] = p0 * Sp[pb + c];
    }
    const float m6 = Mp[pb + 256];
    float pc6 = exp2f((float)j0 * Lp[pb + 256]) * Cp[pb + 256];
    const float m6_2 = m6 * m6;
    const float m6_4 = m6_2 * m6_2;

    float2* outbase = (float2*)out + (size_t)item * 16384;

    for (int t = 0; t < 4; ++t) {
        const int j = j0 + (t<<2);
        const float gf = (j > 0) ? 1.0f : 0.0f;
        const float g = (lane & 1) ? -gf : gf;

        // ---- phase 1: S (regs) and V -> bufB.  S=(m+g)p(c,s), V=(m-g)p(c,s)
        float2 S[4];
#pragma unroll
        for (int r = 0; r < 4; ++r) {
            int c = lane + (r<<6);
            float mpc = mg[r] * pcf[r], mps = mg[r] * psf[r];
            float2 Sv = make_float2(fmaf(g, pcf[r], mpc), fmaf(g, psf[r], mps));
            float2 Vv = make_float2(fmaf(-g, pcf[r], mpc), fmaf(-g, psf[r], mps));
            if (c == 0) { Sv.y = 0.0f; Vv.y = 0.0f; }
            S[r] = Sv;
            bufB[c] = Vv;
        }
        const float S6 = fmaf(gf, pc6, m6 * pc6);
        const float V6 = fmaf(-gf, pc6, m6 * pc6);
        if (lane == 0) bufB[256] = make_float2(V6, 0.0f);
        cfence();

        // ---- phase 2: H[c] = 0.5 S - 0.25 (V[c-1]+V[c+1]) -> bufA
#pragma unroll
        for (int r = 0; r < 4; ++r) {
            int c = lane + (r<<6);
            float2 Vm;
            if (c == 0) { float2 v1 = bufB[1]; Vm = make_float2(v1.x, -v1.y); }
            else Vm = bufB[c-1];
            float2 Vp = bufB[c+1];
            bufA[c] = make_float2(0.5f*S[r].x - 0.25f*(Vm.x + Vp.x),
                                  0.5f*S[r].y - 0.25f*(Vm.y + Vp.y));
        }
        if (lane == 0) {
            float2 v255 = bufB[255];
            bufA[256] = make_float2(0.5f*S6 - 0.5f*v255.x, 0.0f);
        }
        cfence();

        // ---- phase 3: half-size packing -> Z (regs); zwr derived from zw0
        float2 Z[4];
#pragma unroll
        for (int r = 0; r < 4; ++r) {
            int k = lane + (r<<6);
            float2 Hk = bufA[k];
            float2 Hm = bufA[256-k];
            const float C45 = 0.70710678118654752f;
            float2 w;
            if      (r == 0) w = zw0;
            else if (r == 1) w = make_float2(C45*(zw0.x - zw0.y),  C45*(zw0.x + zw0.y));
            else if (r == 2) w = make_float2(-zw0.y, zw0.x);
            else             w = make_float2(-C45*(zw0.x + zw0.y), C45*(zw0.x - zw0.y));
            float Ar = Hk.x + Hm.x, Ai = Hk.y - Hm.y;
            float Br = Hk.x - Hm.x, Bi = Hk.y + Hm.y;
            float iwr = -w.y*Br - w.x*Bi;
            float iwi =  w.x*Br - w.y*Bi;
            Z[r] = make_float2((Ar + iwr)*(1.0f/512.0f), (Ai + iwi)*(1.0f/512.0f));
        }
        cfence();

        // ---- FFT stage 0 (lane-local) -> bufB
        {
            float2 apc = cadd(Z[0], Z[2]), amc = csub(Z[0], Z[2]);
            float2 bpd = cadd(Z[1], Z[3]);
            float2 jb = make_float2(Z[3].y - Z[1].y, Z[1].x - Z[3].x);
            float2 w2 = cmul(s0w1, s0w1);
            float2 w3 = cmul(s0w1, w2);
            const int base = lane << 2;
            bufB[PH(base + 0)] = cadd(apc, bpd);
            bufB[PH(base + 1)] = cmul(s0w1, cadd(amc, jb));
            bufB[PH(base + 2)] = cmul(w2,   csub(apc, bpd));
            bufB[PH(base + 3)] = cmul(w3,   csub(amc, jb));
        }
        cfence();

        // ---- FFT stage 1 (s=4): bufB -> bufA
        {
            float2 A = bufB[PH(lane)];
            float2 B = bufB[PH(lane + 64)];
            float2 C = bufB[PH(lane + 128)];
            float2 D = bufB[PH(lane + 192)];
            float2 apc = cadd(A, C), amc = csub(A, C);
            float2 bpd = cadd(B, D);
            float2 jb = make_float2(D.y - B.y, B.x - D.x);
            float2 w2 = cmul(s1w1, s1w1);
            float2 w3 = cmul(s1w1, w2);
            const int ob = (lane & 3) + ((lane >> 2) << 4);
            bufA[PH(ob)]      = cadd(apc, bpd);
            bufA[PH(ob + 4)]  = cmul(s1w1, cadd(amc, jb));
            bufA[PH(ob + 8)]  = cmul(w2,   csub(apc, bpd));
            bufA[PH(ob + 12)] = cmul(w3,   csub(amc, jb));
        }
        cfence();

        // ---- FFT stage 2 (s=16): bufA -> bufB
        {
            float2 A = bufA[PH(lane)];
            float2 B = bufA[PH(lane + 64)];
            float2 C = bufA[PH(lane + 128)];
            float2 D = bufA[PH(lane + 192)];
            float2 apc = cadd(A, C), amc = csub(A, C);
            float2 bpd = cadd(B, D);
            float2 jb = make_float2(D.y - B.y, B.x - D.x);
            float2 w2 = cmul(s2w1, s2w1);
            float2 w3 = cmul(s2w1, w2);
            const int ob = (lane & 15) + ((lane >> 4) << 6);
            bufB[PH(ob)]      = cadd(apc, bpd);
            bufB[PH(ob + 16)] = cmul(s2w1, cadd(amc, jb));
            bufB[PH(ob + 32)] = cmul(w2,   csub(apc, bpd));
            bufB[PH(ob + 48)] = cmul(w3,   csub(amc, jb));
        }
        cfence();

        // ---- stage 3 fused (twiddles=1, lower half only) + store
        {
            float2 A = bufB[PH(lane)];
            float2 B = bufB[PH(lane + 64)];
            float2 C = bufB[PH(lane + 128)];
            float2 D = bufB[PH(lane + 192)];
            float2 apc = cadd(A, C), amc = csub(A, C);
            float2 bpd = cadd(B, D);
            float2 jb = make_float2(D.y - B.y, B.x - D.x);
            float2 y0 = cadd(apc, bpd);
            float2 y1 = cadd(amc, jb);
            float2* o2 = outbase + (j << 7);
            o2[lane] = y0;
            o2[lane + 64] = y1;
        }
        cfence();

        // advance m^j by m^4 (folded into trig products)
#pragma unroll
        for (int r = 0; r < 4; ++r) { pcf[r] *= m4[r]; psf[r] *= m4[r]; }
        pc6 *= m6_4;
    }
}

extern "C" void kernel_launch(void* const* d_in, const int* in_sizes, int n_in,
                              void* d_out, int out_size, void* d_ws, size_t ws_size,
                              hipStream_t stream)
{
    const float* sel   = (const float*)d_in[0];   // (8,32,4,4096) f32 -> [1024][4096]
    const float* items = (const float*)d_in[1];   // (4096,514) f32
    float* out = (float*)d_out;                   // [1024][32768] f32
    float* ws  = (float*)d_ws;

    // Scratch in d_out (all dead before kres rewrites out):
    float* WT     = out;                          // 4096*1024 = 4,194,304 f
    float* rowmax = out + 4194304;                // 1024
    float* rowinv = out + 4195328;                // 1024
    int*   ncol   = (int*)(out + 4196352);        // 514
    int*   kidx   = (int*)(out + 4196866);        // 514*CAP
    float* kval   = (float*)(out + 4196866 + 514*CAP);
    float* P      = ws;                           // 4*1024*257 floats

    ksoft<<<1024, 256, 0, stream>>>(sel, rowmax, rowinv);
    kT<<<dim3(64, 16), 256, 0, stream>>>(sel, rowmax, rowinv, WT);
    kfill<<<514, 256, 0, stream>>>(items, kidx, kval, ncol);
    kspmm<<<dim3(514, 4), 256, 0, stream>>>(WT, kidx, kval, ncol, P);
    kres<<<8192, 256, 0, stream>>>(P, out);
}

// Round 12
// 132.346 us; speedup vs baseline: 3.6940x; 3.5267x over previous
//
#include <hip/hip_runtime.h>

#define PI_F 3.14159265358979f
#define CAP 256

__device__ __forceinline__ float2 cadd(float2 a, float2 b){ return make_float2(a.x+b.x, a.y+b.y); }
__device__ __forceinline__ float2 csub(float2 a, float2 b){ return make_float2(a.x-b.x, a.y-b.y); }
__device__ __forceinline__ float2 cmul(float2 a, float2 b){ return make_float2(a.x*b.x - a.y*b.y, a.x*b.y + a.y*b.x); }

// XOR swizzle on complex index for FFT ping-pong buffers
#define PH(i) ((i) ^ ((((unsigned)(i))>>5)&7))

// COMPILER-ONLY fence: LDS pipe is in-order per wave (buffers are wave-private),
// so cross-lane visibility needs no hardware drain — only a reorder barrier.
__device__ __forceinline__ void cfence() {
    asm volatile("" ::: "memory");
}

// ---------------- kernel A: per-row softmax stats (max, 1/sumexp) ----------------
__global__ __launch_bounds__(256) void ksoft(const float* __restrict__ sel,
                                             float* __restrict__ rowmax,
                                             float* __restrict__ rowinv)
{
    const int row = blockIdx.x;
    const int tid = threadIdx.x;
    const float4* p4 = (const float4*)(sel + (size_t)row * 4096);
    float4 v[4];
    float mx = -3.0e38f;
#pragma unroll
    for (int i = 0; i < 4; ++i) {
        v[i] = p4[tid + (i<<8)];
        mx = fmaxf(mx, fmaxf(fmaxf(v[i].x, v[i].y), fmaxf(v[i].z, v[i].w)));
    }
#pragma unroll
    for (int o = 32; o >= 1; o >>= 1) mx = fmaxf(mx, __shfl_xor(mx, o));
    __shared__ float red[8];
    const int wv = tid >> 6;
    if ((tid & 63) == 0) red[wv] = mx;
    __syncthreads();
    mx = fmaxf(fmaxf(red[0], red[1]), fmaxf(red[2], red[3]));
    float s = 0.0f;
#pragma unroll
    for (int i = 0; i < 4; ++i) {
        s += __expf(v[i].x - mx) + __expf(v[i].y - mx) + __expf(v[i].z - mx) + __expf(v[i].w - mx);
    }
#pragma unroll
    for (int o = 32; o >= 1; o >>= 1) s += __shfl_xor(s, o);
    if ((tid & 63) == 0) red[4 + wv] = s;
    __syncthreads();
    if (tid == 0) {
        rowmax[row] = mx;
        rowinv[row] = 1.0f / (red[4] + red[5] + red[6] + red[7]);
    }
}

// ---------------- kernel A2: W^T[k][m] = softmax weight, tiled transpose ----------------
__global__ __launch_bounds__(256) void kT(const float* __restrict__ sel,
                                          const float* __restrict__ rowmax,
                                          const float* __restrict__ rowinv,
                                          float* __restrict__ WT)
{
    __shared__ float tile[64][65];
    __shared__ float smx[64], sinv[64];
    const int t = threadIdx.x;
    const int k0 = blockIdx.x * 64;
    const int m0 = blockIdx.y * 64;

    if (t < 64) { smx[t] = rowmax[m0 + t]; sinv[t] = rowinv[m0 + t]; }
    __syncthreads();

    const int m_l = t >> 4;            // 0..15
    const int k_l4 = (t & 15) << 2;    // 0,4,..,60
#pragma unroll
    for (int i = 0; i < 4; ++i) {
        const int ml = m_l + (i << 4);
        const float mxv = smx[ml], invv = sinv[ml];
        float4 v = *(const float4*)(sel + (size_t)(m0 + ml) * 4096 + k0 + k_l4);
        tile[k_l4 + 0][ml] = __expf(v.x - mxv) * invv;
        tile[k_l4 + 1][ml] = __expf(v.y - mxv) * invv;
        tile[k_l4 + 2][ml] = __expf(v.z - mxv) * invv;
        tile[k_l4 + 3][ml] = __expf(v.w - mxv) * invv;
    }
    __syncthreads();

    const int k_l = t >> 2;            // 0..63
    const int mb = (t & 3) << 2;       // 0,4,8,12
#pragma unroll
    for (int i = 0; i < 4; ++i) {
        const int ml = mb + (i << 4);
        float4 w = make_float4(tile[k_l][ml], tile[k_l][ml+1], tile[k_l][ml+2], tile[k_l][ml+3]);
        *(float4*)(WT + (size_t)(k0 + k_l) * 1024 + m0 + ml) = w;
    }
}

// ---------------- kernel B: build per-column nonzero lists of items (deterministic) -----
__global__ __launch_bounds__(256) void kfill(const float* __restrict__ items,
                                             int* __restrict__ kidx,
                                             float* __restrict__ kval,
                                             int* __restrict__ ncol)
{
    const int c = blockIdx.x;
    const int t = threadIdx.x;
    const int wv = t >> 6;
    const int lane = t & 63;
    __shared__ int wcnt[4];

    const int kc0 = wv << 10;
    float vv[16];
    int cnt = 0;
#pragma unroll
    for (int it = 0; it < 16; ++it) {
        const int k = kc0 + (it << 6) + lane;
        const float v = items[(size_t)k * 514 + c];
        vv[it] = v;
        unsigned long long mb = __ballot(v != 0.0f);
        cnt += __popcll(mb);
    }
    if (lane == 0) wcnt[wv] = cnt;
    __syncthreads();

    int base = 0;
#pragma unroll
    for (int q = 0; q < 4; ++q) if (q < wv) base += wcnt[q];

    const unsigned long long ltmask = (lane == 63) ? 0x7fffffffffffffffull
                                                   : ((1ull << lane) - 1ull);
#pragma unroll
    for (int it = 0; it < 16; ++it) {
        const float v = vv[it];
        const bool nz = (v != 0.0f);
        unsigned long long mb = __ballot(nz);
        if (nz) {
            const int slot = base + __popcll(mb & ltmask);
            if (slot < CAP) {
                kidx[c * CAP + slot] = kc0 + (it << 6) + lane;
                kval[c * CAP + slot] = v;
            }
        }
        base += __popcll(mb);
    }
    if (t == 0) ncol[c] = wcnt[0] + wcnt[1] + wcnt[2] + wcnt[3];
}

// ---------------- kernel B2: sparse matmul + transform -> P planes ----------------
__global__ __launch_bounds__(256) void kspmm(const float* __restrict__ WT,
                                             const int* __restrict__ kidx,
                                             const float* __restrict__ kval,
                                             const int* __restrict__ ncol,
                                             float* __restrict__ P)
{
    const int c = blockIdx.x;
    const int m = (blockIdx.y << 8) + threadIdx.x;
    const int nn = min(ncol[c], CAP);
    const int* ki = kidx + c * CAP;
    const float* kv = kval + c * CAP;

    float acc = 0.0f;
    int i = 0;
    for (; i + 4 <= nn; i += 4) {
        const int k0 = ki[i], k1 = ki[i+1], k2 = ki[i+2], k3 = ki[i+3];
        const float v0 = kv[i], v1 = kv[i+1], v2 = kv[i+2], v3 = kv[i+3];
        const float w0 = WT[(size_t)k0 * 1024 + m];
        const float w1 = WT[(size_t)k1 * 1024 + m];
        const float w2 = WT[(size_t)k2 * 1024 + m];
        const float w3 = WT[(size_t)k3 * 1024 + m];
        acc = fmaf(v0, w0, acc);
        acc = fmaf(v1, w1, acc);
        acc = fmaf(v2, w2, acc);
        acc = fmaf(v3, w3, acc);
    }
    for (; i < nn; ++i) {
        acc = fmaf(kv[i], WT[(size_t)ki[i] * 1024 + m], acc);
    }

    float* Lp = P;
    float* Mp = P + 1024*257;
    float* Cp = P + 2*1024*257;
    float* Sp = P + 3*1024*257;
    const float x = acc;
    if (c < 257) {
        float mm = 0.9999f / (1.0f + __expf(-x));
        const int idx = m * 257 + c;
        Lp[idx] = __log2f(mm);
        Mp[idx] = mm;
    } else {
        const int idx = m * 257 + (c - 257);
        float e2 = __expf(2.0f * x);
        float th = (e2 - 1.0f) / (e2 + 1.0f);
        float ph = PI_F * th;
        float sn, cs;
        __sincosf(ph, &sn, &cs);
        Cp[idx] = cs;
        Sp[idx] = sn;
    }
}

// ---------------- kernel C: spectral + IFFT, wave-private LDS, compiler fences only ----------
// Twiddles in an LDS table (R5-style) to keep natural VGPR demand ~55 WITHOUT any
// launch-bounds cap (R10/R11 lesson: capping at demand spill-cascades).
__global__ __launch_bounds__(256) void kres(const float* __restrict__ P, float* __restrict__ out)
{
    const int tid = threadIdx.x;
    const int lane = tid & 63;
    const int wv = tid >> 6;
    const int item = blockIdx.x >> 3;
    const int jg = blockIdx.x & 7;

    __shared__ float2 tw[256];            // e^{+2pi i t/256}
    __shared__ float2 bufA_s[4][257];
    __shared__ float2 bufB_s[4][257];
    float2* bufA = bufA_s[wv];
    float2* bufB = bufB_s[wv];

    {
        float s, c;
        __sincosf((6.283185307179586f/256.0f) * (float)tid, &s, &c);
        tw[tid] = make_float2(c, s);
    }
    __syncthreads();                      // one-time tw init barrier

    // packing twiddle base: zw0 = e^{+2pi i lane/512}; zwr[r] derived inline per r.
    float2 zw0;
    {
        float s, c;
        __sincosf((6.283185307179586f/512.0f) * (float)lane, &s, &c);
        zw0 = make_float2(c, s);
    }

    const float* Lp = P;
    const float* Mp = P + 1024*257;
    const float* Cp = P + 2*1024*257;
    const float* Sp = P + 3*1024*257;
    const int pb = item * 257;
    const int j0 = jg*16 + wv;

    // Persistent per-bin state: pcf = m^j * cos, psf = m^j * sin, mg = m, m4 = m^4.
    float pcf[4], psf[4], mg[4], m4[4];
#pragma unroll
    for (int r = 0; r < 4; ++r) {
        int c = lane + (r<<6);
        float lv = Lp[pb + c];
        mg[r] = Mp[pb + c];
        float m2 = mg[r] * mg[r];
        m4[r] = m2 * m2;
        float p0 = exp2f((float)j0 * lv);
        pcf[r] = p0 * Cp[pb + c];
        psf[r] = p0 * Sp[pb + c];
    }
    const float m6 = Mp[pb + 256];
    float pc6 = exp2f((float)j0 * Lp[pb + 256]) * Cp[pb + 256];
    const float m6_2 = m6 * m6;
    const float m6_4 = m6_2 * m6_2;

    float2* outbase = (float2*)out + (size_t)item * 16384;

    for (int t = 0; t < 4; ++t) {
        const int j = j0 + (t<<2);
        const float gf = (j > 0) ? 1.0f : 0.0f;
        const float g = (lane & 1) ? -gf : gf;

        // ---- phase 1: S (regs) and V -> bufB.  S=(m+g)p(c,s), V=(m-g)p(c,s)
        float2 S[4];
#pragma unroll
        for (int r = 0; r < 4; ++r) {
            int c = lane + (r<<6);
            float mpc = mg[r] * pcf[r], mps = mg[r] * psf[r];
            float2 Sv = make_float2(fmaf(g, pcf[r], mpc), fmaf(g, psf[r], mps));
            float2 Vv = make_float2(fmaf(-g, pcf[r], mpc), fmaf(-g, psf[r], mps));
            if (c == 0) { Sv.y = 0.0f; Vv.y = 0.0f; }
            S[r] = Sv;
            bufB[c] = Vv;
        }
        const float S6 = fmaf(gf, pc6, m6 * pc6);
        const float V6 = fmaf(-gf, pc6, m6 * pc6);
        if (lane == 0) bufB[256] = make_float2(V6, 0.0f);
        cfence();

        // ---- phase 2: H[c] = 0.5 S - 0.25 (V[c-1]+V[c+1]) -> bufA
#pragma unroll
        for (int r = 0; r < 4; ++r) {
            int c = lane + (r<<6);
            float2 Vm;
            if (c == 0) { float2 v1 = bufB[1]; Vm = make_float2(v1.x, -v1.y); }
            else Vm = bufB[c-1];
            float2 Vp = bufB[c+1];
            bufA[c] = make_float2(0.5f*S[r].x - 0.25f*(Vm.x + Vp.x),
                                  0.5f*S[r].y - 0.25f*(Vm.y + Vp.y));
        }
        if (lane == 0) {
            float2 v255 = bufB[255];
            bufA[256] = make_float2(0.5f*S6 - 0.5f*v255.x, 0.0f);
        }
        cfence();

        // ---- phase 3: half-size packing -> Z (regs); zwr derived from zw0
        float2 Z[4];
#pragma unroll
        for (int r = 0; r < 4; ++r) {
            int k = lane + (r<<6);
            float2 Hk = bufA[k];
            float2 Hm = bufA[256-k];
            const float C45 = 0.70710678118654752f;
            float2 w;
            if      (r == 0) w = zw0;
            else if (r == 1) w = make_float2(C45*(zw0.x - zw0.y),  C45*(zw0.x + zw0.y));
            else if (r == 2) w = make_float2(-zw0.y, zw0.x);
            else             w = make_float2(-C45*(zw0.x + zw0.y), C45*(zw0.x - zw0.y));
            float Ar = Hk.x + Hm.x, Ai = Hk.y - Hm.y;
            float Br = Hk.x - Hm.x, Bi = Hk.y + Hm.y;
            float iwr = -w.y*Br - w.x*Bi;
            float iwi =  w.x*Br - w.y*Bi;
            Z[r] = make_float2((Ar + iwr)*(1.0f/512.0f), (Ai + iwi)*(1.0f/512.0f));
        }
        cfence();

        // ---- FFT stage 0 (lane-local) -> bufB; twiddles from LDS table
        {
            float2 apc = cadd(Z[0], Z[2]), amc = csub(Z[0], Z[2]);
            float2 bpd = cadd(Z[1], Z[3]);
            float2 jb = make_float2(Z[3].y - Z[1].y, Z[1].x - Z[3].x);
            float2 w1 = tw[lane], w2 = tw[2*lane], w3 = tw[3*lane];
            const int base = lane << 2;
            bufB[PH(base + 0)] = cadd(apc, bpd);
            bufB[PH(base + 1)] = cmul(w1, cadd(amc, jb));
            bufB[PH(base + 2)] = cmul(w2, csub(apc, bpd));
            bufB[PH(base + 3)] = cmul(w3, csub(amc, jb));
        }
        cfence();

        // ---- FFT stage 1 (s=4): bufB -> bufA
        {
            float2 A = bufB[PH(lane)];
            float2 B = bufB[PH(lane + 64)];
            float2 C = bufB[PH(lane + 128)];
            float2 D = bufB[PH(lane + 192)];
            float2 apc = cadd(A, C), amc = csub(A, C);
            float2 bpd = cadd(B, D);
            float2 jb = make_float2(D.y - B.y, B.x - D.x);
            const int tb = (lane >> 2) << 2;
            float2 w1 = tw[tb], w2 = tw[2*tb], w3 = tw[3*tb];
            const int ob = (lane & 3) + ((lane >> 2) << 4);
            bufA[PH(ob)]      = cadd(apc, bpd);
            bufA[PH(ob + 4)]  = cmul(w1, cadd(amc, jb));
            bufA[PH(ob + 8)]  = cmul(w2, csub(apc, bpd));
            bufA[PH(ob + 12)] = cmul(w3, csub(amc, jb));
        }
        cfence();

        // ---- FFT stage 2 (s=16): bufA -> bufB
        {
            float2 A = bufA[PH(lane)];
            float2 B = bufA[PH(lane + 64)];
            float2 C = bufA[PH(lane + 128)];
            float2 D = bufA[PH(lane + 192)];
            float2 apc = cadd(A, C), amc = csub(A, C);
            float2 bpd = cadd(B, D);
            float2 jb = make_float2(D.y - B.y, B.x - D.x);
            const int tb = (lane >> 4) << 4;
            float2 w1 = tw[tb], w2 = tw[2*tb], w3 = tw[3*tb];
            const int ob = (lane & 15) + ((lane >> 4) << 6);
            bufB[PH(ob)]      = cadd(apc, bpd);
            bufB[PH(ob + 16)] = cmul(w1, cadd(amc, jb));
            bufB[PH(ob + 32)] = cmul(w2, csub(apc, bpd));
            bufB[PH(ob + 48)] = cmul(w3, csub(amc, jb));
        }
        cfence();

        // ---- stage 3 fused (twiddles=1, lower half only) + store
        {
            float2 A = bufB[PH(lane)];
            float2 B = bufB[PH(lane + 64)];
            float2 C = bufB[PH(lane + 128)];
            float2 D = bufB[PH(lane + 192)];
            float2 apc = cadd(A, C), amc = csub(A, C);
            float2 bpd = cadd(B, D);
            float2 jb = make_float2(D.y - B.y, B.x - D.x);
            float2 y0 = cadd(apc, bpd);
            float2 y1 = cadd(amc, jb);
            float2* o2 = outbase + (j << 7);
            o2[lane] = y0;
            o2[lane + 64] = y1;
        }
        cfence();

        // advance m^j by m^4 (folded into trig products)
#pragma unroll
        for (int r = 0; r < 4; ++r) { pcf[r] *= m4[r]; psf[r] *= m4[r]; }
        pc6 *= m6_4;
    }
}

extern "C" void kernel_launch(void* const* d_in, const int* in_sizes, int n_in,
                              void* d_out, int out_size, void* d_ws, size_t ws_size,
                              hipStream_t stream)
{
    const float* sel   = (const float*)d_in[0];   // (8,32,4,4096) f32 -> [1024][4096]
    const float* items = (const float*)d_in[1];   // (4096,514) f32
    float* out = (float*)d_out;                   // [1024][32768] f32
    float* ws  = (float*)d_ws;

    // Scratch in d_out (all dead before kres rewrites out):
    float* WT     = out;                          // 4096*1024 = 4,194,304 f
    float* rowmax = out + 4194304;                // 1024
    float* rowinv = out + 4195328;                // 1024
    int*   ncol   = (int*)(out + 4196352);        // 514
    int*   kidx   = (int*)(out + 4196866);        // 514*CAP
    float* kval   = (float*)(out + 4196866 + 514*CAP);
    float* P      = ws;                           // 4*1024*257 floats

    ksoft<<<1024, 256, 0, stream>>>(sel, rowmax, rowinv);
    kT<<<dim3(64, 16), 256, 0, stream>>>(sel, rowmax, rowinv, WT);
    kfill<<<514, 256, 0, stream>>>(items, kidx, kval, ncol);
    kspmm<<<dim3(514, 4), 256, 0, stream>>>(WT, kidx, kval, ncol, P);
    kres<<<8192, 256, 0, stream>>>(P, out);
}

// Round 13
// 116.122 us; speedup vs baseline: 4.2101x; 1.1397x over previous
//
#include <hip/hip_runtime.h>

#define PI_F 3.14159265358979f
#define CAP 256

__device__ __forceinline__ float2 cadd(float2 a, float2 b){ return make_float2(a.x+b.x, a.y+b.y); }
__device__ __forceinline__ float2 csub(float2 a, float2 b){ return make_float2(a.x-b.x, a.y-b.y); }
__device__ __forceinline__ float2 cmul(float2 a, float2 b){ return make_float2(a.x*b.x - a.y*b.y, a.x*b.y + a.y*b.x); }

// COMPILER-ONLY fence: LDS pipe is in-order per wave (buffers are wave-private),
// so cross-lane visibility needs no hardware drain — only a reorder barrier.
__device__ __forceinline__ void cfence() {
    asm volatile("" ::: "memory");
}

// ---- 16-pt unnormalized inverse DFT (sign +), in-place, fully unrolled ----
// Y[a] = sum_b x[b] e^{+2pi i a b/16}; radix-4 x radix-4.
#define W16_C8 0.923879532511287f
#define W16_S8 0.382683432365090f
#define W16_R2 0.707106781186548f
__device__ __forceinline__ void idft16_full(float2* x)
{
    float2 u[16];
#pragma unroll
    for (int b0 = 0; b0 < 4; ++b0) {
        float2 x0 = x[b0], x1 = x[4+b0], x2 = x[8+b0], x3 = x[12+b0];
        float2 t0 = cadd(x0,x2), t1 = csub(x0,x2);
        float2 t2 = cadd(x1,x3), t3 = csub(x1,x3);
        float2 it3 = make_float2(-t3.y, t3.x);
        u[b0*4+0] = cadd(t0,t2);
        u[b0*4+1] = cadd(t1,it3);
        u[b0*4+2] = csub(t0,t2);
        u[b0*4+3] = csub(t1,it3);
    }
    // twiddles W16^{b0*a0}
    u[4+1]  = cmul(u[4+1],  make_float2( W16_C8,  W16_S8));   // W^1
    u[4+2]  = cmul(u[4+2],  make_float2( W16_R2,  W16_R2));   // W^2
    u[4+3]  = cmul(u[4+3],  make_float2( W16_S8,  W16_C8));   // W^3
    u[8+1]  = cmul(u[8+1],  make_float2( W16_R2,  W16_R2));   // W^2
    { float2 v = u[8+2]; u[8+2] = make_float2(-v.y, v.x); }   // W^4 = i
    u[8+3]  = cmul(u[8+3],  make_float2(-W16_R2,  W16_R2));   // W^6
    u[12+1] = cmul(u[12+1], make_float2( W16_S8,  W16_C8));   // W^3
    u[12+2] = cmul(u[12+2], make_float2(-W16_R2,  W16_R2));   // W^6
    u[12+3] = cmul(u[12+3], make_float2(-W16_C8, -W16_S8));   // W^9
#pragma unroll
    for (int a0 = 0; a0 < 4; ++a0) {
        float2 x0 = u[a0], x1 = u[4+a0], x2 = u[8+a0], x3 = u[12+a0];
        float2 t0 = cadd(x0,x2), t1 = csub(x0,x2);
        float2 t2 = cadd(x1,x3), t3 = csub(x1,x3);
        float2 it3 = make_float2(-t3.y, t3.x);
        x[a0+0]  = cadd(t0,t2);
        x[a0+4]  = cadd(t1,it3);
        x[a0+8]  = csub(t0,t2);
        x[a0+12] = csub(t1,it3);
    }
}
// low-8 variant: only outputs a = 0..7 (a1 in {0,1})
__device__ __forceinline__ void idft16_low8(float2* x)
{
    float2 u[16];
#pragma unroll
    for (int b0 = 0; b0 < 4; ++b0) {
        float2 x0 = x[b0], x1 = x[4+b0], x2 = x[8+b0], x3 = x[12+b0];
        float2 t0 = cadd(x0,x2), t1 = csub(x0,x2);
        float2 t2 = cadd(x1,x3), t3 = csub(x1,x3);
        float2 it3 = make_float2(-t3.y, t3.x);
        u[b0*4+0] = cadd(t0,t2);
        u[b0*4+1] = cadd(t1,it3);
        u[b0*4+2] = csub(t0,t2);
        u[b0*4+3] = csub(t1,it3);
    }
    u[4+1]  = cmul(u[4+1],  make_float2( W16_C8,  W16_S8));
    u[4+2]  = cmul(u[4+2],  make_float2( W16_R2,  W16_R2));
    u[4+3]  = cmul(u[4+3],  make_float2( W16_S8,  W16_C8));
    u[8+1]  = cmul(u[8+1],  make_float2( W16_R2,  W16_R2));
    { float2 v = u[8+2]; u[8+2] = make_float2(-v.y, v.x); }
    u[8+3]  = cmul(u[8+3],  make_float2(-W16_R2,  W16_R2));
    u[12+1] = cmul(u[12+1], make_float2( W16_S8,  W16_C8));
    u[12+2] = cmul(u[12+2], make_float2(-W16_R2,  W16_R2));
    u[12+3] = cmul(u[12+3], make_float2(-W16_C8, -W16_S8));
#pragma unroll
    for (int a0 = 0; a0 < 4; ++a0) {
        float2 x0 = u[a0], x1 = u[4+a0], x2 = u[8+a0], x3 = u[12+a0];
        float2 t0 = cadd(x0,x2), t1 = csub(x0,x2);
        float2 t2 = cadd(x1,x3), t3 = csub(x1,x3);
        float2 it3 = make_float2(-t3.y, t3.x);
        x[a0+0] = cadd(t0,t2);
        x[a0+4] = cadd(t1,it3);
    }
}

// ---------------- kernel A: per-row softmax stats (max, 1/sumexp) ----------------
__global__ __launch_bounds__(256) void ksoft(const float* __restrict__ sel,
                                             float* __restrict__ rowmax,
                                             float* __restrict__ rowinv)
{
    const int row = blockIdx.x;
    const int tid = threadIdx.x;
    const float4* p4 = (const float4*)(sel + (size_t)row * 4096);
    float4 v[4];
    float mx = -3.0e38f;
#pragma unroll
    for (int i = 0; i < 4; ++i) {
        v[i] = p4[tid + (i<<8)];
        mx = fmaxf(mx, fmaxf(fmaxf(v[i].x, v[i].y), fmaxf(v[i].z, v[i].w)));
    }
#pragma unroll
    for (int o = 32; o >= 1; o >>= 1) mx = fmaxf(mx, __shfl_xor(mx, o));
    __shared__ float red[8];
    const int wv = tid >> 6;
    if ((tid & 63) == 0) red[wv] = mx;
    __syncthreads();
    mx = fmaxf(fmaxf(red[0], red[1]), fmaxf(red[2], red[3]));
    float s = 0.0f;
#pragma unroll
    for (int i = 0; i < 4; ++i) {
        s += __expf(v[i].x - mx) + __expf(v[i].y - mx) + __expf(v[i].z - mx) + __expf(v[i].w - mx);
    }
#pragma unroll
    for (int o = 32; o >= 1; o >>= 1) s += __shfl_xor(s, o);
    if ((tid & 63) == 0) red[4 + wv] = s;
    __syncthreads();
    if (tid == 0) {
        rowmax[row] = mx;
        rowinv[row] = 1.0f / (red[4] + red[5] + red[6] + red[7]);
    }
}

// ---------------- kernel A2: W^T[k][m] = softmax weight, tiled transpose ----------------
__global__ __launch_bounds__(256) void kT(const float* __restrict__ sel,
                                          const float* __restrict__ rowmax,
                                          const float* __restrict__ rowinv,
                                          float* __restrict__ WT)
{
    __shared__ float tile[64][65];
    __shared__ float smx[64], sinv[64];
    const int t = threadIdx.x;
    const int k0 = blockIdx.x * 64;
    const int m0 = blockIdx.y * 64;

    if (t < 64) { smx[t] = rowmax[m0 + t]; sinv[t] = rowinv[m0 + t]; }
    __syncthreads();

    const int m_l = t >> 4;
    const int k_l4 = (t & 15) << 2;
#pragma unroll
    for (int i = 0; i < 4; ++i) {
        const int ml = m_l + (i << 4);
        const float mxv = smx[ml], invv = sinv[ml];
        float4 v = *(const float4*)(sel + (size_t)(m0 + ml) * 4096 + k0 + k_l4);
        tile[k_l4 + 0][ml] = __expf(v.x - mxv) * invv;
        tile[k_l4 + 1][ml] = __expf(v.y - mxv) * invv;
        tile[k_l4 + 2][ml] = __expf(v.z - mxv) * invv;
        tile[k_l4 + 3][ml] = __expf(v.w - mxv) * invv;
    }
    __syncthreads();

    const int k_l = t >> 2;
    const int mb = (t & 3) << 2;
#pragma unroll
    for (int i = 0; i < 4; ++i) {
        const int ml = mb + (i << 4);
        float4 w = make_float4(tile[k_l][ml], tile[k_l][ml+1], tile[k_l][ml+2], tile[k_l][ml+3]);
        *(float4*)(WT + (size_t)(k0 + k_l) * 1024 + m0 + ml) = w;
    }
}

// ---------------- kernel B: build per-column nonzero lists of items (deterministic) -----
__global__ __launch_bounds__(256) void kfill(const float* __restrict__ items,
                                             int* __restrict__ kidx,
                                             float* __restrict__ kval,
                                             int* __restrict__ ncol)
{
    const int c = blockIdx.x;
    const int t = threadIdx.x;
    const int wv = t >> 6;
    const int lane = t & 63;
    __shared__ int wcnt[4];

    const int kc0 = wv << 10;
    float vv[16];
    int cnt = 0;
#pragma unroll
    for (int it = 0; it < 16; ++it) {
        const int k = kc0 + (it << 6) + lane;
        const float v = items[(size_t)k * 514 + c];
        vv[it] = v;
        unsigned long long mb = __ballot(v != 0.0f);
        cnt += __popcll(mb);
    }
    if (lane == 0) wcnt[wv] = cnt;
    __syncthreads();

    int base = 0;
#pragma unroll
    for (int q = 0; q < 4; ++q) if (q < wv) base += wcnt[q];

    const unsigned long long ltmask = (lane == 63) ? 0x7fffffffffffffffull
                                                   : ((1ull << lane) - 1ull);
#pragma unroll
    for (int it = 0; it < 16; ++it) {
        const float v = vv[it];
        const bool nz = (v != 0.0f);
        unsigned long long mb = __ballot(nz);
        if (nz) {
            const int slot = base + __popcll(mb & ltmask);
            if (slot < CAP) {
                kidx[c * CAP + slot] = kc0 + (it << 6) + lane;
                kval[c * CAP + slot] = v;
            }
        }
        base += __popcll(mb);
    }
    if (t == 0) ncol[c] = wcnt[0] + wcnt[1] + wcnt[2] + wcnt[3];
}

// ---------------- kernel B2: sparse matmul + transform -> P4 (float4 {L,M,C,S} per bin) ----
__global__ __launch_bounds__(256) void kspmm(const float* __restrict__ WT,
                                             const int* __restrict__ kidx,
                                             const float* __restrict__ kval,
                                             const int* __restrict__ ncol,
                                             float2* __restrict__ P2)
{
    const int c = blockIdx.x;
    const int m = (blockIdx.y << 8) + threadIdx.x;
    const int nn = min(ncol[c], CAP);
    const int* ki = kidx + c * CAP;
    const float* kv = kval + c * CAP;

    float acc = 0.0f;
    int i = 0;
    for (; i + 4 <= nn; i += 4) {
        const int k0 = ki[i], k1 = ki[i+1], k2 = ki[i+2], k3 = ki[i+3];
        const float v0 = kv[i], v1 = kv[i+1], v2 = kv[i+2], v3 = kv[i+3];
        const float w0 = WT[(size_t)k0 * 1024 + m];
        const float w1 = WT[(size_t)k1 * 1024 + m];
        const float w2 = WT[(size_t)k2 * 1024 + m];
        const float w3 = WT[(size_t)k3 * 1024 + m];
        acc = fmaf(v0, w0, acc);
        acc = fmaf(v1, w1, acc);
        acc = fmaf(v2, w2, acc);
        acc = fmaf(v3, w3, acc);
    }
    for (; i < nn; ++i) {
        acc = fmaf(kv[i], WT[(size_t)ki[i] * 1024 + m], acc);
    }

    const float x = acc;
    if (c < 257) {
        float mm = 0.9999f / (1.0f + __expf(-x));
        P2[((size_t)m * 257 + c) * 2] = make_float2(__log2f(mm), mm);
    } else {
        float e2 = __expf(2.0f * x);
        float th = (e2 - 1.0f) / (e2 + 1.0f);
        float ph = PI_F * th;
        float sn, cs;
        __sincosf(ph, &sn, &cs);
        P2[((size_t)m * 257 + (c - 257)) * 2 + 1] = make_float2(cs, sn);
    }
}

// ---------------- kernel C: 16 lanes per j-block, radix-16^2 IFFT, 1 LDS transpose -------
// block = (item, jg); 4 waves x 4 groups = 16 j's. Lane gl holds bins c = gl+16r, r=0..15.
// Union LDS buffer per (wave,group), 276 float2 (group stride 276 -> base%16 = 4g, bank-perfect).
__global__ __launch_bounds__(256) void kres(const float4* __restrict__ P4, float* __restrict__ out)
{
    const int tid = threadIdx.x;
    const int lane = tid & 63;
    const int wv = tid >> 6;
    const int g = lane >> 4;
    const int gl = lane & 15;
    const int item = blockIdx.x >> 3;
    const int jg = blockIdx.x & 7;

    __shared__ float2 U[16 * 276];
    float2* ub = U + (wv * 4 + g) * 276;

    const int j = jg * 16 + wv * 4 + g;
    const float fj = (float)j;
    const float gf = (j > 0) ? 1.0f : 0.0f;
    const float sg = (gl & 1) ? -gf : gf;     // (-1)^c * gf, c = gl+16r

    const int pb4 = item * 257;

    // ---- phase 1: load bins, build S (regs) and V -> LDS
    float2 S[16];
#pragma unroll
    for (int r = 0; r < 16; ++r) {
        float4 q = P4[pb4 + gl + 16*r];       // {L, M, C, S}
        float p = exp2f(fj * q.x);
        float pc = p * q.z, ps = p * q.w;
        float mpc = q.y * pc, mps = q.y * ps;
        float2 Sv = make_float2(fmaf(sg, pc, mpc), fmaf(sg, ps, mps));
        float2 Vv = make_float2(fmaf(-sg, pc, mpc), fmaf(-sg, ps, mps));
        if (gl == 0 && r == 0) { Sv.y = 0.0f; Vv.y = 0.0f; }  // DC imag dropped
        S[r] = Sv;
        ub[gl + 16*r] = Vv;
    }
    // bin 256 (computed by all lanes, written by gl==0)
    float4 q6 = P4[pb4 + 256];
    float pc6 = exp2f(fj * q6.x) * q6.z;
    const float S6 = (q6.y + gf) * pc6;
    const float V6 = (q6.y - gf) * pc6;
    if (gl == 0) ub[256] = make_float2(V6, 0.0f);
    cfence();

    // ---- phase 2: Hann 3-tap, H into S regs (no LDS write yet)
    float H6;
#pragma unroll
    for (int r = 0; r < 16; ++r) {
        const int c = gl + 16*r;
        const int im = (c == 0) ? 1 : c - 1;
        float2 Vm = ub[im];
        if (c == 0) Vm.y = -Vm.y;             // hermitian V[-1] = conj V[1]
        float2 Vp = ub[c + 1];
        S[r] = make_float2(0.5f*S[r].x - 0.25f*(Vm.x + Vp.x),
                           0.5f*S[r].y - 0.25f*(Vm.y + Vp.y));
    }
    H6 = 0.5f*S6 - 0.5f*ub[255].x;            // read before overwrite
    cfence();

    // write H over V (same-wave in-order; all V reads above precede these stores)
#pragma unroll
    for (int r = 0; r < 16; ++r) ub[gl + 16*r] = S[r];
    if (gl == 0) ub[256] = make_float2(H6, 0.0f);
    cfence();

    // ---- phase 3: half-size packing -> Z (into S regs)
    float2 w;
    {
        float s, c;
        __sincosf((6.283185307179586f/512.0f) * (float)gl, &s, &c);
        w = make_float2(c, s);                // e^{2pi i gl/512}
    }
    const float2 om = make_float2(0.980785280403230f, 0.195090322016128f); // e^{i pi/16}
#pragma unroll
    for (int r = 0; r < 16; ++r) {
        const int c = gl + 16*r;
        float2 Hk = S[r];
        float2 Hm = ub[256 - c];              // uniform mirror (c=0 -> slot 256)
        float Ar = Hk.x + Hm.x, Ai = Hk.y - Hm.y;
        float Br = Hk.x - Hm.x, Bi = Hk.y + Hm.y;
        float iwr = -w.y*Br - w.x*Bi;
        float iwi =  w.x*Br - w.y*Bi;
        S[r] = make_float2((Ar + iwr)*(1.0f/512.0f), (Ai + iwi)*(1.0f/512.0f));
        w = cmul(w, om);
    }
    cfence();   // all HB reads done before transpose writes (same buffer)

    // ---- FFT step 1: lane-local 16-pt IDFT over k2 (register axis); k1 = gl
    idft16_full(S);

    // ---- twiddle e^{2pi i k1 n1/256} + transpose write
    {
        float2 wt;
        float s, c;
        __sincosf((6.283185307179586f/256.0f) * (float)gl, &s, &c);
        wt = make_float2(c, s);
        float2 ww = make_float2(1.0f, 0.0f);
#pragma unroll
        for (int n1 = 0; n1 < 16; ++n1) {
            ub[gl*17 + n1] = cmul(S[n1], ww);
            ww = cmul(ww, wt);
        }
    }
    cfence();

    // ---- transpose read: lane gl becomes n1 = gl; T[k1]
    float2 T[16];
#pragma unroll
    for (int k1 = 0; k1 < 16; ++k1) T[k1] = ub[k1*17 + gl];

    // ---- FFT step 2: lane-local 16-pt IDFT over k1, outputs n2 = 0..7 only
    idft16_low8(T);

    // ---- store: z[n1 + 16 n2] -> out float2 slot (j<<7) + gl + 16*n2
    float2* o2 = (float2*)out + (size_t)item * 16384 + (j << 7);
#pragma unroll
    for (int n2 = 0; n2 < 8; ++n2) o2[gl + 16*n2] = T[n2];
}

extern "C" void kernel_launch(void* const* d_in, const int* in_sizes, int n_in,
                              void* d_out, int out_size, void* d_ws, size_t ws_size,
                              hipStream_t stream)
{
    const float* sel   = (const float*)d_in[0];   // (8,32,4,4096) f32 -> [1024][4096]
    const float* items = (const float*)d_in[1];   // (4096,514) f32
    float* out = (float*)d_out;                   // [1024][32768] f32
    float* ws  = (float*)d_ws;

    // Scratch in d_out (all dead before kres rewrites out):
    float* WT     = out;                          // 4096*1024 floats
    float* rowmax = out + 4194304;                // 1024
    float* rowinv = out + 4195328;                // 1024
    int*   ncol   = (int*)(out + 4196352);        // 514
    int*   kidx   = (int*)(out + 4196866);        // 514*CAP
    float* kval   = (float*)(out + 4196866 + 514*CAP);
    // P4 in ws: 1024*257 float4 = same float count as previous 4-plane P
    float4* P4    = (float4*)ws;

    ksoft<<<1024, 256, 0, stream>>>(sel, rowmax, rowinv);
    kT<<<dim3(64, 16), 256, 0, stream>>>(sel, rowmax, rowinv, WT);
    kfill<<<514, 256, 0, stream>>>(items, kidx, kval, ncol);
    kspmm<<<dim3(514, 4), 256, 0, stream>>>(WT, kidx, kval, ncol, (float2*)ws);
    kres<<<8192, 256, 0, stream>>>(P4, out);
}

// Round 14
// 112.254 us; speedup vs baseline: 4.3552x; 1.0345x over previous
//
#include <hip/hip_runtime.h>

#define PI_F 3.14159265358979f
#define CAP 256

#if __has_builtin(__builtin_amdgcn_exp2f)
#define EXP2F(x) __builtin_amdgcn_exp2f(x)
#else
#define EXP2F(x) exp2f(x)
#endif

__device__ __forceinline__ float2 cadd(float2 a, float2 b){ return make_float2(a.x+b.x, a.y+b.y); }
__device__ __forceinline__ float2 csub(float2 a, float2 b){ return make_float2(a.x-b.x, a.y-b.y); }
__device__ __forceinline__ float2 cmul(float2 a, float2 b){ return make_float2(a.x*b.x - a.y*b.y, a.x*b.y + a.y*b.x); }

// COMPILER-ONLY fence: LDS pipe is in-order per wave (buffers are wave-private),
// so cross-lane visibility needs no hardware drain — only a reorder barrier.
__device__ __forceinline__ void cfence() {
    asm volatile("" ::: "memory");
}

// ---- 16-pt unnormalized inverse DFT (sign +), in-place, fully unrolled ----
#define W16_C8 0.923879532511287f
#define W16_S8 0.382683432365090f
#define W16_R2 0.707106781186548f
__device__ __forceinline__ void idft16_full(float2* x)
{
    float2 u[16];
#pragma unroll
    for (int b0 = 0; b0 < 4; ++b0) {
        float2 x0 = x[b0], x1 = x[4+b0], x2 = x[8+b0], x3 = x[12+b0];
        float2 t0 = cadd(x0,x2), t1 = csub(x0,x2);
        float2 t2 = cadd(x1,x3), t3 = csub(x1,x3);
        float2 it3 = make_float2(-t3.y, t3.x);
        u[b0*4+0] = cadd(t0,t2);
        u[b0*4+1] = cadd(t1,it3);
        u[b0*4+2] = csub(t0,t2);
        u[b0*4+3] = csub(t1,it3);
    }
    u[4+1]  = cmul(u[4+1],  make_float2( W16_C8,  W16_S8));
    u[4+2]  = cmul(u[4+2],  make_float2( W16_R2,  W16_R2));
    u[4+3]  = cmul(u[4+3],  make_float2( W16_S8,  W16_C8));
    u[8+1]  = cmul(u[8+1],  make_float2( W16_R2,  W16_R2));
    { float2 v = u[8+2]; u[8+2] = make_float2(-v.y, v.x); }
    u[8+3]  = cmul(u[8+3],  make_float2(-W16_R2,  W16_R2));
    u[12+1] = cmul(u[12+1], make_float2( W16_S8,  W16_C8));
    u[12+2] = cmul(u[12+2], make_float2(-W16_R2,  W16_R2));
    u[12+3] = cmul(u[12+3], make_float2(-W16_C8, -W16_S8));
#pragma unroll
    for (int a0 = 0; a0 < 4; ++a0) {
        float2 x0 = u[a0], x1 = u[4+a0], x2 = u[8+a0], x3 = u[12+a0];
        float2 t0 = cadd(x0,x2), t1 = csub(x0,x2);
        float2 t2 = cadd(x1,x3), t3 = csub(x1,x3);
        float2 it3 = make_float2(-t3.y, t3.x);
        x[a0+0]  = cadd(t0,t2);
        x[a0+4]  = cadd(t1,it3);
        x[a0+8]  = csub(t0,t2);
        x[a0+12] = csub(t1,it3);
    }
}
__device__ __forceinline__ void idft16_low8(float2* x)
{
    float2 u[16];
#pragma unroll
    for (int b0 = 0; b0 < 4; ++b0) {
        float2 x0 = x[b0], x1 = x[4+b0], x2 = x[8+b0], x3 = x[12+b0];
        float2 t0 = cadd(x0,x2), t1 = csub(x0,x2);
        float2 t2 = cadd(x1,x3), t3 = csub(x1,x3);
        float2 it3 = make_float2(-t3.y, t3.x);
        u[b0*4+0] = cadd(t0,t2);
        u[b0*4+1] = cadd(t1,it3);
        u[b0*4+2] = csub(t0,t2);
        u[b0*4+3] = csub(t1,it3);
    }
    u[4+1]  = cmul(u[4+1],  make_float2( W16_C8,  W16_S8));
    u[4+2]  = cmul(u[4+2],  make_float2( W16_R2,  W16_R2));
    u[4+3]  = cmul(u[4+3],  make_float2( W16_S8,  W16_C8));
    u[8+1]  = cmul(u[8+1],  make_float2( W16_R2,  W16_R2));
    { float2 v = u[8+2]; u[8+2] = make_float2(-v.y, v.x); }
    u[8+3]  = cmul(u[8+3],  make_float2(-W16_R2,  W16_R2));
    u[12+1] = cmul(u[12+1], make_float2( W16_S8,  W16_C8));
    u[12+2] = cmul(u[12+2], make_float2(-W16_R2,  W16_R2));
    u[12+3] = cmul(u[12+3], make_float2(-W16_C8, -W16_S8));
#pragma unroll
    for (int a0 = 0; a0 < 4; ++a0) {
        float2 x0 = u[a0], x1 = u[4+a0], x2 = u[8+a0], x3 = u[12+a0];
        float2 t0 = cadd(x0,x2), t1 = csub(x0,x2);
        float2 t2 = cadd(x1,x3), t3 = csub(x1,x3);
        float2 it3 = make_float2(-t3.y, t3.x);
        x[a0+0] = cadd(t0,t2);
        x[a0+4] = cadd(t1,it3);
    }
}

// ---------------- kernel A: per-row softmax stats (max, 1/sumexp) ----------------
__global__ __launch_bounds__(256) void ksoft(const float* __restrict__ sel,
                                             float* __restrict__ rowmax,
                                             float* __restrict__ rowinv)
{
    const int row = blockIdx.x;
    const int tid = threadIdx.x;
    const float4* p4 = (const float4*)(sel + (size_t)row * 4096);
    float4 v[4];
    float mx = -3.0e38f;
#pragma unroll
    for (int i = 0; i < 4; ++i) {
        v[i] = p4[tid + (i<<8)];
        mx = fmaxf(mx, fmaxf(fmaxf(v[i].x, v[i].y), fmaxf(v[i].z, v[i].w)));
    }
#pragma unroll
    for (int o = 32; o >= 1; o >>= 1) mx = fmaxf(mx, __shfl_xor(mx, o));
    __shared__ float red[8];
    const int wv = tid >> 6;
    if ((tid & 63) == 0) red[wv] = mx;
    __syncthreads();
    mx = fmaxf(fmaxf(red[0], red[1]), fmaxf(red[2], red[3]));
    float s = 0.0f;
#pragma unroll
    for (int i = 0; i < 4; ++i) {
        s += __expf(v[i].x - mx) + __expf(v[i].y - mx) + __expf(v[i].z - mx) + __expf(v[i].w - mx);
    }
#pragma unroll
    for (int o = 32; o >= 1; o >>= 1) s += __shfl_xor(s, o);
    if ((tid & 63) == 0) red[4 + wv] = s;
    __syncthreads();
    if (tid == 0) {
        rowmax[row] = mx;
        rowinv[row] = 1.0f / (red[4] + red[5] + red[6] + red[7]);
    }
}

// ---------------- kernel A2: W^T[k][m] = softmax weight, tiled transpose ----------------
__global__ __launch_bounds__(256) void kT(const float* __restrict__ sel,
                                          const float* __restrict__ rowmax,
                                          const float* __restrict__ rowinv,
                                          float* __restrict__ WT)
{
    __shared__ float tile[64][65];
    __shared__ float smx[64], sinv[64];
    const int t = threadIdx.x;
    const int k0 = blockIdx.x * 64;
    const int m0 = blockIdx.y * 64;

    if (t < 64) { smx[t] = rowmax[m0 + t]; sinv[t] = rowinv[m0 + t]; }
    __syncthreads();

    const int m_l = t >> 4;
    const int k_l4 = (t & 15) << 2;
#pragma unroll
    for (int i = 0; i < 4; ++i) {
        const int ml = m_l + (i << 4);
        const float mxv = smx[ml], invv = sinv[ml];
        float4 v = *(const float4*)(sel + (size_t)(m0 + ml) * 4096 + k0 + k_l4);
        tile[k_l4 + 0][ml] = __expf(v.x - mxv) * invv;
        tile[k_l4 + 1][ml] = __expf(v.y - mxv) * invv;
        tile[k_l4 + 2][ml] = __expf(v.z - mxv) * invv;
        tile[k_l4 + 3][ml] = __expf(v.w - mxv) * invv;
    }
    __syncthreads();

    const int k_l = t >> 2;
    const int mb = (t & 3) << 2;
#pragma unroll
    for (int i = 0; i < 4; ++i) {
        const int ml = mb + (i << 4);
        float4 w = make_float4(tile[k_l][ml], tile[k_l][ml+1], tile[k_l][ml+2], tile[k_l][ml+3]);
        *(float4*)(WT + (size_t)(k0 + k_l) * 1024 + m0 + ml) = w;
    }
}

// ---------------- kernel B: build per-column nonzero lists of items (deterministic) -----
__global__ __launch_bounds__(256) void kfill(const float* __restrict__ items,
                                             int* __restrict__ kidx,
                                             float* __restrict__ kval,
                                             int* __restrict__ ncol)
{
    const int c = blockIdx.x;
    const int t = threadIdx.x;
    const int wv = t >> 6;
    const int lane = t & 63;
    __shared__ int wcnt[4];

    const int kc0 = wv << 10;
    float vv[16];
    int cnt = 0;
#pragma unroll
    for (int it = 0; it < 16; ++it) {
        const int k = kc0 + (it << 6) + lane;
        const float v = items[(size_t)k * 514 + c];
        vv[it] = v;
        unsigned long long mb = __ballot(v != 0.0f);
        cnt += __popcll(mb);
    }
    if (lane == 0) wcnt[wv] = cnt;
    __syncthreads();

    int base = 0;
#pragma unroll
    for (int q = 0; q < 4; ++q) if (q < wv) base += wcnt[q];

    const unsigned long long ltmask = (lane == 63) ? 0x7fffffffffffffffull
                                                   : ((1ull << lane) - 1ull);
#pragma unroll
    for (int it = 0; it < 16; ++it) {
        const float v = vv[it];
        const bool nz = (v != 0.0f);
        unsigned long long mb = __ballot(nz);
        if (nz) {
            const int slot = base + __popcll(mb & ltmask);
            if (slot < CAP) {
                kidx[c * CAP + slot] = kc0 + (it << 6) + lane;
                kval[c * CAP + slot] = v;
            }
        }
        base += __popcll(mb);
    }
    if (t == 0) ncol[c] = wcnt[0] + wcnt[1] + wcnt[2] + wcnt[3];
}

// ---------------- kernel B2: sparse matmul + transform -> P4 (float4 {L,M,C,S} per bin) ----
// (k,v) list staged in LDS: coalesced load once, then uniform broadcast reads.
__global__ __launch_bounds__(256) void kspmm(const float* __restrict__ WT,
                                             const int* __restrict__ kidx,
                                             const float* __restrict__ kval,
                                             const int* __restrict__ ncol,
                                             float2* __restrict__ P2)
{
    __shared__ int   ski[CAP];
    __shared__ float skv[CAP];
    const int c = blockIdx.x;
    const int m = (blockIdx.y << 8) + threadIdx.x;
    const int nn = min(ncol[c], CAP);
    if (threadIdx.x < nn) {
        ski[threadIdx.x] = kidx[c * CAP + threadIdx.x];
        skv[threadIdx.x] = kval[c * CAP + threadIdx.x];
    }
    __syncthreads();

    float acc = 0.0f;
    int i = 0;
    for (; i + 4 <= nn; i += 4) {
        const int k0 = ski[i], k1 = ski[i+1], k2 = ski[i+2], k3 = ski[i+3];
        const float v0 = skv[i], v1 = skv[i+1], v2 = skv[i+2], v3 = skv[i+3];
        const float w0 = WT[(size_t)k0 * 1024 + m];
        const float w1 = WT[(size_t)k1 * 1024 + m];
        const float w2 = WT[(size_t)k2 * 1024 + m];
        const float w3 = WT[(size_t)k3 * 1024 + m];
        acc = fmaf(v0, w0, acc);
        acc = fmaf(v1, w1, acc);
        acc = fmaf(v2, w2, acc);
        acc = fmaf(v3, w3, acc);
    }
    for (; i < nn; ++i) {
        acc = fmaf(skv[i], WT[(size_t)ski[i] * 1024 + m], acc);
    }

    const float x = acc;
    if (c < 257) {
        float mm = 0.9999f / (1.0f + __expf(-x));
        P2[((size_t)m * 257 + c) * 2] = make_float2(__log2f(mm), mm);
    } else {
        float e2 = __expf(2.0f * x);
        float th = (e2 - 1.0f) / (e2 + 1.0f);
        float ph = PI_F * th;
        float sn, cs;
        __sincosf(ph, &sn, &cs);
        P2[((size_t)m * 257 + (c - 257)) * 2 + 1] = make_float2(cs, sn);
    }
}

// ---------------- kernel C: 16 lanes per j-block, radix-16^2 IFFT, 1 LDS transpose -------
__global__ __launch_bounds__(256) void kres(const float4* __restrict__ P4, float* __restrict__ out)
{
    const int tid = threadIdx.x;
    const int lane = tid & 63;
    const int wv = tid >> 6;
    const int g = lane >> 4;
    const int gl = lane & 15;
    const int item = blockIdx.x >> 3;
    const int jg = blockIdx.x & 7;

    __shared__ float2 U[16 * 276];
    float2* ub = U + (wv * 4 + g) * 276;

    const int j = jg * 16 + wv * 4 + g;
    const float fj = (float)j;
    const float gf = (j > 0) ? 1.0f : 0.0f;
    const float sg = (gl & 1) ? -gf : gf;     // (-1)^c * gf, c = gl+16r

    const int pb4 = item * 257;

    // ---- phase 1: load bins, build S (regs) and V -> LDS
    float2 S[16];
#pragma unroll
    for (int r = 0; r < 16; ++r) {
        float4 q = P4[pb4 + gl + 16*r];       // {L, M, C, S}
        float p = EXP2F(fj * q.x);
        float pc = p * q.z, ps = p * q.w;
        float mpc = q.y * pc, mps = q.y * ps;
        float2 Sv = make_float2(fmaf(sg, pc, mpc), fmaf(sg, ps, mps));
        float2 Vv = make_float2(fmaf(-sg, pc, mpc), fmaf(-sg, ps, mps));
        if (gl == 0 && r == 0) { Sv.y = 0.0f; Vv.y = 0.0f; }  // DC imag dropped
        S[r] = Sv;
        ub[gl + 16*r] = Vv;
    }
    float4 q6 = P4[pb4 + 256];
    float pc6 = EXP2F(fj * q6.x) * q6.z;
    const float S6 = (q6.y + gf) * pc6;
    const float V6 = (q6.y - gf) * pc6;
    if (gl == 0) ub[256] = make_float2(V6, 0.0f);
    cfence();

    // ---- phase 2: Hann 3-tap, H into S regs
    float H6;
#pragma unroll
    for (int r = 0; r < 16; ++r) {
        const int c = gl + 16*r;
        const int im = (c == 0) ? 1 : c - 1;
        float2 Vm = ub[im];
        if (c == 0) Vm.y = -Vm.y;             // hermitian V[-1] = conj V[1]
        float2 Vp = ub[c + 1];
        S[r] = make_float2(0.5f*S[r].x - 0.25f*(Vm.x + Vp.x),
                           0.5f*S[r].y - 0.25f*(Vm.y + Vp.y));
    }
    H6 = 0.5f*S6 - 0.5f*ub[255].x;            // read before overwrite
    cfence();

    // write H over V (same-wave in-order)
#pragma unroll
    for (int r = 0; r < 16; ++r) ub[gl + 16*r] = S[r];
    if (gl == 0) ub[256] = make_float2(H6, 0.0f);
    cfence();

    // ---- phase 3: half-size packing -> Z (into S regs)
    // w_r = zw0 * e^{2pi i r/32}; constants unrolled (no serial chain)
    float2 zw0;
    {
        float s, c;
        __sincosf((6.283185307179586f/512.0f) * (float)gl, &s, &c);
        zw0 = make_float2(c, s);
    }
    const float ZKC[16] = { 1.0f, 0.980785280403230f, 0.923879532511287f, 0.831469612302545f,
                            0.707106781186548f, 0.555570233019602f, 0.382683432365090f, 0.195090322016128f,
                            0.0f, -0.195090322016128f, -0.382683432365090f, -0.555570233019602f,
                            -0.707106781186548f, -0.831469612302545f, -0.923879532511287f, -0.980785280403230f };
    const float ZKS[16] = { 0.0f, 0.195090322016128f, 0.382683432365090f, 0.555570233019602f,
                            0.707106781186548f, 0.831469612302545f, 0.923879532511287f, 0.980785280403230f,
                            1.0f, 0.980785280403230f, 0.923879532511287f, 0.831469612302545f,
                            0.707106781186548f, 0.555570233019602f, 0.382683432365090f, 0.195090322016128f };
#pragma unroll
    for (int r = 0; r < 16; ++r) {
        const int c = gl + 16*r;
        float2 Hk = S[r];
        float2 Hm = ub[256 - c];              // uniform mirror (c=0 -> slot 256)
        float2 w = make_float2(ZKC[r]*zw0.x - ZKS[r]*zw0.y,
                               ZKC[r]*zw0.y + ZKS[r]*zw0.x);
        float Ar = Hk.x + Hm.x, Ai = Hk.y - Hm.y;
        float Br = Hk.x - Hm.x, Bi = Hk.y + Hm.y;
        float iwr = -w.y*Br - w.x*Bi;
        float iwi =  w.x*Br - w.y*Bi;
        S[r] = make_float2((Ar + iwr)*(1.0f/512.0f), (Ai + iwi)*(1.0f/512.0f));
    }
    cfence();   // all reads done before transpose writes (same buffer)

    // ---- FFT step 1: lane-local 16-pt IDFT over k2 (register axis); k1 = gl
    idft16_full(S);

    // ---- twiddle e^{2pi i k1 n1/256} + transpose write
    {
        float2 wt;
        float s, c;
        __sincosf((6.283185307179586f/256.0f) * (float)gl, &s, &c);
        wt = make_float2(c, s);
        float2 ww = make_float2(1.0f, 0.0f);
#pragma unroll
        for (int n1 = 0; n1 < 16; ++n1) {
            ub[gl*17 + n1] = cmul(S[n1], ww);
            ww = cmul(ww, wt);
        }
    }
    cfence();

    // ---- transpose read: lane gl becomes n1 = gl; T[k1]
    float2 T[16];
#pragma unroll
    for (int k1 = 0; k1 < 16; ++k1) T[k1] = ub[k1*17 + gl];

    // ---- FFT step 2: lane-local 16-pt IDFT over k1, outputs n2 = 0..7 only
    idft16_low8(T);

    // ---- store: z[n1 + 16 n2] -> out float2 slot (j<<7) + gl + 16*n2
    float2* o2 = (float2*)out + (size_t)item * 16384 + (j << 7);
#pragma unroll
    for (int n2 = 0; n2 < 8; ++n2) o2[gl + 16*n2] = T[n2];
}

extern "C" void kernel_launch(void* const* d_in, const int* in_sizes, int n_in,
                              void* d_out, int out_size, void* d_ws, size_t ws_size,
                              hipStream_t stream)
{
    const float* sel   = (const float*)d_in[0];   // (8,32,4,4096) f32 -> [1024][4096]
    const float* items = (const float*)d_in[1];   // (4096,514) f32
    float* out = (float*)d_out;                   // [1024][32768] f32
    float* ws  = (float*)d_ws;

    // Scratch in d_out (all dead before kres rewrites out):
    float* WT     = out;                          // 4096*1024 floats
    float* rowmax = out + 4194304;                // 1024
    float* rowinv = out + 4195328;                // 1024
    int*   ncol   = (int*)(out + 4196352);        // 514
    int*   kidx   = (int*)(out + 4196866);        // 514*CAP
    float* kval   = (float*)(out + 4196866 + 514*CAP);
    float4* P4    = (float4*)ws;                  // 1024*257 float4

    ksoft<<<1024, 256, 0, stream>>>(sel, rowmax, rowinv);
    kT<<<dim3(64, 16), 256, 0, stream>>>(sel, rowmax, rowinv, WT);
    kfill<<<514, 256, 0, stream>>>(items, kidx, kval, ncol);
    kspmm<<<dim3(514, 4), 256, 0, stream>>>(WT, kidx, kval, ncol, (float2*)ws);
    kres<<<8192, 256, 0, stream>>>(P4, out);
}

// Round 15
// 105.859 us; speedup vs baseline: 4.6183x; 1.0604x over previous
//
#include <hip/hip_runtime.h>

#define PI_F 3.14159265358979f
#define CAP 256

#if __has_builtin(__builtin_amdgcn_exp2f)
#define EXP2F(x) __builtin_amdgcn_exp2f(x)
#else
#define EXP2F(x) exp2f(x)
#endif

// ---- packed complex type: <2 x float> so the backend can select v_pk_*_f32 ----
typedef float cf2 __attribute__((ext_vector_type(2)));
__device__ __forceinline__ cf2 mkc(float x, float y){ cf2 r; r.x = x; r.y = y; return r; }
__device__ __forceinline__ cf2 cmulv(cf2 a, cf2 b){
    cf2 bs = mkc(-b.y, b.x);
#if __has_builtin(__builtin_elementwise_fma)
    return __builtin_elementwise_fma(a.yy, bs, a.xx * b);
#else
    return a.xx * b + a.yy * bs;
#endif
}
__device__ __forceinline__ cf2 cjg(cf2 a){ return mkc(a.x, -a.y); }
__device__ __forceinline__ cf2 ci(cf2 a){ return mkc(-a.y, a.x); }   // i*a

// COMPILER-ONLY fence: LDS pipe is in-order per wave (buffers are wave-private),
// so cross-lane visibility needs no hardware drain — only a reorder barrier.
__device__ __forceinline__ void cfence() {
    asm volatile("" ::: "memory");
}

// ---- 16-pt unnormalized inverse DFT (sign +), in-place, fully unrolled ----
#define W16_C8 0.923879532511287f
#define W16_S8 0.382683432365090f
#define W16_R2 0.707106781186548f
__device__ __forceinline__ void idft16_full(cf2* x)
{
    cf2 u[16];
#pragma unroll
    for (int b0 = 0; b0 < 4; ++b0) {
        cf2 x0 = x[b0], x1 = x[4+b0], x2 = x[8+b0], x3 = x[12+b0];
        cf2 t0 = x0 + x2, t1 = x0 - x2;
        cf2 t2 = x1 + x3, t3 = x1 - x3;
        cf2 it3 = ci(t3);
        u[b0*4+0] = t0 + t2;
        u[b0*4+1] = t1 + it3;
        u[b0*4+2] = t0 - t2;
        u[b0*4+3] = t1 - it3;
    }
    u[4+1]  = cmulv(u[4+1],  mkc( W16_C8,  W16_S8));
    u[4+2]  = cmulv(u[4+2],  mkc( W16_R2,  W16_R2));
    u[4+3]  = cmulv(u[4+3],  mkc( W16_S8,  W16_C8));
    u[8+1]  = cmulv(u[8+1],  mkc( W16_R2,  W16_R2));
    u[8+2]  = ci(u[8+2]);
    u[8+3]  = cmulv(u[8+3],  mkc(-W16_R2,  W16_R2));
    u[12+1] = cmulv(u[12+1], mkc( W16_S8,  W16_C8));
    u[12+2] = cmulv(u[12+2], mkc(-W16_R2,  W16_R2));
    u[12+3] = cmulv(u[12+3], mkc(-W16_C8, -W16_S8));
#pragma unroll
    for (int a0 = 0; a0 < 4; ++a0) {
        cf2 x0 = u[a0], x1 = u[4+a0], x2 = u[8+a0], x3 = u[12+a0];
        cf2 t0 = x0 + x2, t1 = x0 - x2;
        cf2 t2 = x1 + x3, t3 = x1 - x3;
        cf2 it3 = ci(t3);
        x[a0+0]  = t0 + t2;
        x[a0+4]  = t1 + it3;
        x[a0+8]  = t0 - t2;
        x[a0+12] = t1 - it3;
    }
}
__device__ __forceinline__ void idft16_low8(cf2* x)
{
    cf2 u[16];
#pragma unroll
    for (int b0 = 0; b0 < 4; ++b0) {
        cf2 x0 = x[b0], x1 = x[4+b0], x2 = x[8+b0], x3 = x[12+b0];
        cf2 t0 = x0 + x2, t1 = x0 - x2;
        cf2 t2 = x1 + x3, t3 = x1 - x3;
        cf2 it3 = ci(t3);
        u[b0*4+0] = t0 + t2;
        u[b0*4+1] = t1 + it3;
        u[b0*4+2] = t0 - t2;
        u[b0*4+3] = t1 - it3;
    }
    u[4+1]  = cmulv(u[4+1],  mkc( W16_C8,  W16_S8));
    u[4+2]  = cmulv(u[4+2],  mkc( W16_R2,  W16_R2));
    u[4+3]  = cmulv(u[4+3],  mkc( W16_S8,  W16_C8));
    u[8+1]  = cmulv(u[8+1],  mkc( W16_R2,  W16_R2));
    u[8+2]  = ci(u[8+2]);
    u[8+3]  = cmulv(u[8+3],  mkc(-W16_R2,  W16_R2));
    u[12+1] = cmulv(u[12+1], mkc( W16_S8,  W16_C8));
    u[12+2] = cmulv(u[12+2], mkc(-W16_R2,  W16_R2));
    u[12+3] = cmulv(u[12+3], mkc(-W16_C8, -W16_S8));
#pragma unroll
    for (int a0 = 0; a0 < 4; ++a0) {
        cf2 x0 = u[a0], x1 = u[4+a0], x2 = u[8+a0], x3 = u[12+a0];
        cf2 t0 = x0 + x2, t1 = x0 - x2;
        cf2 t2 = x1 + x3, t3 = x1 - x3;
        cf2 it3 = ci(t3);
        x[a0+0] = t0 + t2;
        x[a0+4] = t1 + it3;
    }
}

// ---------------- kernel A: per-row softmax stats (max, 1/sumexp) ----------------
__global__ __launch_bounds__(256) void ksoft(const float* __restrict__ sel,
                                             float* __restrict__ rowmax,
                                             float* __restrict__ rowinv)
{
    const int row = blockIdx.x;
    const int tid = threadIdx.x;
    const float4* p4 = (const float4*)(sel + (size_t)row * 4096);
    float4 v[4];
    float mx = -3.0e38f;
#pragma unroll
    for (int i = 0; i < 4; ++i) {
        v[i] = p4[tid + (i<<8)];
        mx = fmaxf(mx, fmaxf(fmaxf(v[i].x, v[i].y), fmaxf(v[i].z, v[i].w)));
    }
#pragma unroll
    for (int o = 32; o >= 1; o >>= 1) mx = fmaxf(mx, __shfl_xor(mx, o));
    __shared__ float red[8];
    const int wv = tid >> 6;
    if ((tid & 63) == 0) red[wv] = mx;
    __syncthreads();
    mx = fmaxf(fmaxf(red[0], red[1]), fmaxf(red[2], red[3]));
    float s = 0.0f;
#pragma unroll
    for (int i = 0; i < 4; ++i) {
        s += __expf(v[i].x - mx) + __expf(v[i].y - mx) + __expf(v[i].z - mx) + __expf(v[i].w - mx);
    }
#pragma unroll
    for (int o = 32; o >= 1; o >>= 1) s += __shfl_xor(s, o);
    if ((tid & 63) == 0) red[4 + wv] = s;
    __syncthreads();
    if (tid == 0) {
        rowmax[row] = mx;
        rowinv[row] = 1.0f / (red[4] + red[5] + red[6] + red[7]);
    }
}

// ---------------- kernel A2: W^T[k][m] = softmax weight, tiled transpose ----------------
__global__ __launch_bounds__(256) void kT(const float* __restrict__ sel,
                                          const float* __restrict__ rowmax,
                                          const float* __restrict__ rowinv,
                                          float* __restrict__ WT)
{
    __shared__ float tile[64][65];
    __shared__ float smx[64], sinv[64];
    const int t = threadIdx.x;
    const int k0 = blockIdx.x * 64;
    const int m0 = blockIdx.y * 64;

    if (t < 64) { smx[t] = rowmax[m0 + t]; sinv[t] = rowinv[m0 + t]; }
    __syncthreads();

    const int m_l = t >> 4;
    const int k_l4 = (t & 15) << 2;
#pragma unroll
    for (int i = 0; i < 4; ++i) {
        const int ml = m_l + (i << 4);
        const float mxv = smx[ml], invv = sinv[ml];
        float4 v = *(const float4*)(sel + (size_t)(m0 + ml) * 4096 + k0 + k_l4);
        tile[k_l4 + 0][ml] = __expf(v.x - mxv) * invv;
        tile[k_l4 + 1][ml] = __expf(v.y - mxv) * invv;
        tile[k_l4 + 2][ml] = __expf(v.z - mxv) * invv;
        tile[k_l4 + 3][ml] = __expf(v.w - mxv) * invv;
    }
    __syncthreads();

    const int k_l = t >> 2;
    const int mb = (t & 3) << 2;
#pragma unroll
    for (int i = 0; i < 4; ++i) {
        const int ml = mb + (i << 4);
        float4 w = make_float4(tile[k_l][ml], tile[k_l][ml+1], tile[k_l][ml+2], tile[k_l][ml+3]);
        *(float4*)(WT + (size_t)(k0 + k_l) * 1024 + m0 + ml) = w;
    }
}

// ---------------- kernel B: build per-column nonzero lists of items (deterministic) -----
__global__ __launch_bounds__(256) void kfill(const float* __restrict__ items,
                                             int* __restrict__ kidx,
                                             float* __restrict__ kval,
                                             int* __restrict__ ncol)
{
    const int c = blockIdx.x;
    const int t = threadIdx.x;
    const int wv = t >> 6;
    const int lane = t & 63;
    __shared__ int wcnt[4];

    const int kc0 = wv << 10;
    float vv[16];
    int cnt = 0;
#pragma unroll
    for (int it = 0; it < 16; ++it) {
        const int k = kc0 + (it << 6) + lane;
        const float v = items[(size_t)k * 514 + c];
        vv[it] = v;
        unsigned long long mb = __ballot(v != 0.0f);
        cnt += __popcll(mb);
    }
    if (lane == 0) wcnt[wv] = cnt;
    __syncthreads();

    int base = 0;
#pragma unroll
    for (int q = 0; q < 4; ++q) if (q < wv) base += wcnt[q];

    const unsigned long long ltmask = (lane == 63) ? 0x7fffffffffffffffull
                                                   : ((1ull << lane) - 1ull);
#pragma unroll
    for (int it = 0; it < 16; ++it) {
        const float v = vv[it];
        const bool nz = (v != 0.0f);
        unsigned long long mb = __ballot(nz);
        if (nz) {
            const int slot = base + __popcll(mb & ltmask);
            if (slot < CAP) {
                kidx[c * CAP + slot] = kc0 + (it << 6) + lane;
                kval[c * CAP + slot] = v;
            }
        }
        base += __popcll(mb);
    }
    if (t == 0) ncol[c] = wcnt[0] + wcnt[1] + wcnt[2] + wcnt[3];
}

// ---------------- kernel B2: sparse matmul + transform -> P4 (float4 {L,M,C,S} per bin) ----
__global__ __launch_bounds__(256) void kspmm(const float* __restrict__ WT,
                                             const int* __restrict__ kidx,
                                             const float* __restrict__ kval,
                                             const int* __restrict__ ncol,
                                             float2* __restrict__ P2)
{
    __shared__ int   ski[CAP];
    __shared__ float skv[CAP];
    const int c = blockIdx.x;
    const int m = (blockIdx.y << 8) + threadIdx.x;
    const int nn = min(ncol[c], CAP);
    if (threadIdx.x < nn) {
        ski[threadIdx.x] = kidx[c * CAP + threadIdx.x];
        skv[threadIdx.x] = kval[c * CAP + threadIdx.x];
    }
    __syncthreads();

    float acc = 0.0f;
    int i = 0;
    for (; i + 4 <= nn; i += 4) {
        const int k0 = ski[i], k1 = ski[i+1], k2 = ski[i+2], k3 = ski[i+3];
        const float v0 = skv[i], v1 = skv[i+1], v2 = skv[i+2], v3 = skv[i+3];
        const float w0 = WT[(size_t)k0 * 1024 + m];
        const float w1 = WT[(size_t)k1 * 1024 + m];
        const float w2 = WT[(size_t)k2 * 1024 + m];
        const float w3 = WT[(size_t)k3 * 1024 + m];
        acc = fmaf(v0, w0, acc);
        acc = fmaf(v1, w1, acc);
        acc = fmaf(v2, w2, acc);
        acc = fmaf(v3, w3, acc);
    }
    for (; i < nn; ++i) {
        acc = fmaf(skv[i], WT[(size_t)ski[i] * 1024 + m], acc);
    }

    const float x = acc;
    if (c < 257) {
        float mm = 0.9999f / (1.0f + __expf(-x));
        P2[((size_t)m * 257 + c) * 2] = make_float2(__log2f(mm), mm);
    } else {
        float e2 = __expf(2.0f * x);
        float th = (e2 - 1.0f) / (e2 + 1.0f);
        float ph = PI_F * th;
        float sn, cs;
        __sincosf(ph, &sn, &cs);
        P2[((size_t)m * 257 + (c - 257)) * 2 + 1] = make_float2(cs, sn);
    }
}

// ---------------- kernel C: 16 lanes per j-block, radix-16^2 IFFT, packed-f32 complex ----
__global__ __launch_bounds__(256) void kres(const float4* __restrict__ P4, float* __restrict__ out)
{
    const int tid = threadIdx.x;
    const int lane = tid & 63;
    const int wv = tid >> 6;
    const int g = lane >> 4;
    const int gl = lane & 15;
    const int item = blockIdx.x >> 3;
    const int jg = blockIdx.x & 7;

    __shared__ cf2 U[16 * 276];
    cf2* ub = U + (wv * 4 + g) * 276;

    const int j = jg * 16 + wv * 4 + g;
    const float fj = (float)j;
    const float gf = (j > 0) ? 1.0f : 0.0f;
    const float sg = (gl & 1) ? -gf : gf;     // (-1)^c * gf, c = gl+16r

    const int pb4 = item * 257;

    // ---- phase 1: load bins, build S (regs) and V -> LDS
    cf2 S[16];
#pragma unroll
    for (int r = 0; r < 16; ++r) {
        float4 q = P4[pb4 + gl + 16*r];       // {L, M, C, S}
        float p = EXP2F(fj * q.x);
        cf2 F = p * mkc(q.z, q.w);
        cf2 Sv = (q.y + sg) * F;
        cf2 Vv = (q.y - sg) * F;
        if (gl == 0 && r == 0) { Sv.y = 0.0f; Vv.y = 0.0f; }  // DC imag dropped
        S[r] = Sv;
        ub[gl + 16*r] = Vv;
    }
    float4 q6 = P4[pb4 + 256];
    float pc6 = EXP2F(fj * q6.x) * q6.z;
    const float S6 = (q6.y + gf) * pc6;
    const float V6 = (q6.y - gf) * pc6;
    if (gl == 0) ub[256] = mkc(V6, 0.0f);
    cfence();

    // ---- phase 2: Hann 3-tap, H into S regs
    float H6;
#pragma unroll
    for (int r = 0; r < 16; ++r) {
        const int c = gl + 16*r;
        const int im = (c == 0) ? 1 : c - 1;
        cf2 Vm = ub[im];
        if (c == 0) Vm.y = -Vm.y;             // hermitian V[-1] = conj V[1]
        cf2 Vp = ub[c + 1];
        S[r] = 0.5f * S[r] - 0.25f * (Vm + Vp);
    }
    H6 = 0.5f*S6 - 0.5f*ub[255].x;            // read before overwrite
    cfence();

    // write H over V (same-wave in-order)
#pragma unroll
    for (int r = 0; r < 16; ++r) ub[gl + 16*r] = S[r];
    if (gl == 0) ub[256] = mkc(H6, 0.0f);
    cfence();

    // ---- phase 3: half-size packing -> Z (into S regs)
    cf2 zw0;
    {
        float s, c;
        __sincosf((6.283185307179586f/512.0f) * (float)gl, &s, &c);
        zw0 = mkc(c, s);
    }
    const float ZKC[16] = { 1.0f, 0.980785280403230f, 0.923879532511287f, 0.831469612302545f,
                            0.707106781186548f, 0.555570233019602f, 0.382683432365090f, 0.195090322016128f,
                            0.0f, -0.195090322016128f, -0.382683432365090f, -0.555570233019602f,
                            -0.707106781186548f, -0.831469612302545f, -0.923879532511287f, -0.980785280403230f };
    const float ZKS[16] = { 0.0f, 0.195090322016128f, 0.382683432365090f, 0.555570233019602f,
                            0.707106781186548f, 0.831469612302545f, 0.923879532511287f, 0.980785280403230f,
                            1.0f, 0.980785280403230f, 0.923879532511287f, 0.831469612302545f,
                            0.707106781186548f, 0.555570233019602f, 0.382683432365090f, 0.195090322016128f };
#pragma unroll
    for (int r = 0; r < 16; ++r) {
        const int c = gl + 16*r;
        cf2 Hk = S[r];
        cf2 cHm = cjg(ub[256 - c]);           // uniform mirror (c=0 -> slot 256)
        cf2 w = cmulv(mkc(ZKC[r], ZKS[r]), zw0);
        cf2 A = Hk + cHm;
        cf2 B = Hk - cHm;
        S[r] = (A + cmulv(ci(w), B)) * (1.0f/512.0f);
    }
    cfence();   // all reads done before transpose writes (same buffer)

    // ---- FFT step 1: lane-local 16-pt IDFT over k2 (register axis); k1 = gl
    idft16_full(S);

    // ---- twiddle e^{2pi i k1 n1/256} + transpose write
    {
        cf2 wt;
        float s, c;
        __sincosf((6.283185307179586f/256.0f) * (float)gl, &s, &c);
        wt = mkc(c, s);
        cf2 ww = mkc(1.0f, 0.0f);
#pragma unroll
        for (int n1 = 0; n1 < 16; ++n1) {
            ub[gl*17 + n1] = cmulv(S[n1], ww);
            ww = cmulv(ww, wt);
        }
    }
    cfence();

    // ---- transpose read: lane gl becomes n1 = gl; T[k1]
    cf2 T[16];
#pragma unroll
    for (int k1 = 0; k1 < 16; ++k1) T[k1] = ub[k1*17 + gl];

    // ---- FFT step 2: lane-local 16-pt IDFT over k1, outputs n2 = 0..7 only
    idft16_low8(T);

    // ---- store: z[n1 + 16 n2] -> out cf2 slot (j<<7) + gl + 16*n2
    cf2* o2 = (cf2*)out + (size_t)item * 16384 + (j << 7);
#pragma unroll
    for (int n2 = 0; n2 < 8; ++n2) o2[gl + 16*n2] = T[n2];
}

extern "C" void kernel_launch(void* const* d_in, const int* in_sizes, int n_in,
                              void* d_out, int out_size, void* d_ws, size_t ws_size,
                              hipStream_t stream)
{
    const float* sel   = (const float*)d_in[0];   // (8,32,4,4096) f32 -> [1024][4096]
    const float* items = (const float*)d_in[1];   // (4096,514) f32
    float* out = (float*)d_out;                   // [1024][32768] f32
    float* ws  = (float*)d_ws;

    // Scratch in d_out (all dead before kres rewrites out):
    float* WT     = out;                          // 4096*1024 floats
    float* rowmax = out + 4194304;                // 1024
    float* rowinv = out + 4195328;                // 1024
    int*   ncol   = (int*)(out + 4196352);        // 514
    int*   kidx   = (int*)(out + 4196866);        // 514*CAP
    float* kval   = (float*)(out + 4196866 + 514*CAP);
    float4* P4    = (float4*)ws;                  // 1024*257 float4

    ksoft<<<1024, 256, 0, stream>>>(sel, rowmax, rowinv);
    kT<<<dim3(64, 16), 256, 0, stream>>>(sel, rowmax, rowinv, WT);
    kfill<<<514, 256, 0, stream>>>(items, kidx, kval, ncol);
    kspmm<<<dim3(514, 4), 256, 0, stream>>>(WT, kidx, kval, ncol, (float2*)ws);
    kres<<<8192, 256, 0, stream>>>(P4, out);
}

// Round 16
// 103.555 us; speedup vs baseline: 4.7211x; 1.0223x over previous
//
#include <hip/hip_runtime.h>

#define PI_F 3.14159265358979f
#define CAP 256

#if __has_builtin(__builtin_amdgcn_exp2f)
#define EXP2F(x) __builtin_amdgcn_exp2f(x)
#else
#define EXP2F(x) exp2f(x)
#endif

// ---- packed complex type: <2 x float> so the backend can select v_pk_*_f32 ----
typedef float cf2 __attribute__((ext_vector_type(2)));
__device__ __forceinline__ cf2 mkc(float x, float y){ cf2 r; r.x = x; r.y = y; return r; }
__device__ __forceinline__ cf2 cmulv(cf2 a, cf2 b){
    cf2 bs = mkc(-b.y, b.x);
#if __has_builtin(__builtin_elementwise_fma)
    return __builtin_elementwise_fma(a.yy, bs, a.xx * b);
#else
    return a.xx * b + a.yy * bs;
#endif
}
__device__ __forceinline__ cf2 cjg(cf2 a){ return mkc(a.x, -a.y); }
__device__ __forceinline__ cf2 ci(cf2 a){ return mkc(-a.y, a.x); }   // i*a

// COMPILER-ONLY fence: LDS pipe is in-order per wave (buffers are wave-private),
// so cross-lane visibility needs no hardware drain — only a reorder barrier.
__device__ __forceinline__ void cfence() {
    asm volatile("" ::: "memory");
}

// ---- 16-pt unnormalized inverse DFT (sign +), in-place, fully unrolled ----
#define W16_C8 0.923879532511287f
#define W16_S8 0.382683432365090f
#define W16_R2 0.707106781186548f
__device__ __forceinline__ void idft16_full(cf2* x)
{
    cf2 u[16];
#pragma unroll
    for (int b0 = 0; b0 < 4; ++b0) {
        cf2 x0 = x[b0], x1 = x[4+b0], x2 = x[8+b0], x3 = x[12+b0];
        cf2 t0 = x0 + x2, t1 = x0 - x2;
        cf2 t2 = x1 + x3, t3 = x1 - x3;
        cf2 it3 = ci(t3);
        u[b0*4+0] = t0 + t2;
        u[b0*4+1] = t1 + it3;
        u[b0*4+2] = t0 - t2;
        u[b0*4+3] = t1 - it3;
    }
    u[4+1]  = cmulv(u[4+1],  mkc( W16_C8,  W16_S8));
    u[4+2]  = cmulv(u[4+2],  mkc( W16_R2,  W16_R2));
    u[4+3]  = cmulv(u[4+3],  mkc( W16_S8,  W16_C8));
    u[8+1]  = cmulv(u[8+1],  mkc( W16_R2,  W16_R2));
    u[8+2]  = ci(u[8+2]);
    u[8+3]  = cmulv(u[8+3],  mkc(-W16_R2,  W16_R2));
    u[12+1] = cmulv(u[12+1], mkc( W16_S8,  W16_C8));
    u[12+2] = cmulv(u[12+2], mkc(-W16_R2,  W16_R2));
    u[12+3] = cmulv(u[12+3], mkc(-W16_C8, -W16_S8));
#pragma unroll
    for (int a0 = 0; a0 < 4; ++a0) {
        cf2 x0 = u[a0], x1 = u[4+a0], x2 = u[8+a0], x3 = u[12+a0];
        cf2 t0 = x0 + x2, t1 = x0 - x2;
        cf2 t2 = x1 + x3, t3 = x1 - x3;
        cf2 it3 = ci(t3);
        x[a0+0]  = t0 + t2;
        x[a0+4]  = t1 + it3;
        x[a0+8]  = t0 - t2;
        x[a0+12] = t1 - it3;
    }
}
__device__ __forceinline__ void idft16_low8(cf2* x)
{
    cf2 u[16];
#pragma unroll
    for (int b0 = 0; b0 < 4; ++b0) {
        cf2 x0 = x[b0], x1 = x[4+b0], x2 = x[8+b0], x3 = x[12+b0];
        cf2 t0 = x0 + x2, t1 = x0 - x2;
        cf2 t2 = x1 + x3, t3 = x1 - x3;
        cf2 it3 = ci(t3);
        u[b0*4+0] = t0 + t2;
        u[b0*4+1] = t1 + it3;
        u[b0*4+2] = t0 - t2;
        u[b0*4+3] = t1 - it3;
    }
    u[4+1]  = cmulv(u[4+1],  mkc( W16_C8,  W16_S8));
    u[4+2]  = cmulv(u[4+2],  mkc( W16_R2,  W16_R2));
    u[4+3]  = cmulv(u[4+3],  mkc( W16_S8,  W16_C8));
    u[8+1]  = cmulv(u[8+1],  mkc( W16_R2,  W16_R2));
    u[8+2]  = ci(u[8+2]);
    u[8+3]  = cmulv(u[8+3],  mkc(-W16_R2,  W16_R2));
    u[12+1] = cmulv(u[12+1], mkc( W16_S8,  W16_C8));
    u[12+2] = cmulv(u[12+2], mkc(-W16_R2,  W16_R2));
    u[12+3] = cmulv(u[12+3], mkc(-W16_C8, -W16_S8));
#pragma unroll
    for (int a0 = 0; a0 < 4; ++a0) {
        cf2 x0 = u[a0], x1 = u[4+a0], x2 = u[8+a0], x3 = u[12+a0];
        cf2 t0 = x0 + x2, t1 = x0 - x2;
        cf2 t2 = x1 + x3, t3 = x1 - x3;
        cf2 it3 = ci(t3);
        x[a0+0] = t0 + t2;
        x[a0+4] = t1 + it3;
    }
}

// ---------------- kernel A: per-row softmax stats (max, 1/sumexp) ----------------
__global__ __launch_bounds__(256) void ksoft(const float* __restrict__ sel,
                                             float* __restrict__ rowmax,
                                             float* __restrict__ rowinv)
{
    const int row = blockIdx.x;
    const int tid = threadIdx.x;
    const float4* p4 = (const float4*)(sel + (size_t)row * 4096);
    float4 v[4];
    float mx = -3.0e38f;
#pragma unroll
    for (int i = 0; i < 4; ++i) {
        v[i] = p4[tid + (i<<8)];
        mx = fmaxf(mx, fmaxf(fmaxf(v[i].x, v[i].y), fmaxf(v[i].z, v[i].w)));
    }
#pragma unroll
    for (int o = 32; o >= 1; o >>= 1) mx = fmaxf(mx, __shfl_xor(mx, o));
    __shared__ float red[8];
    const int wv = tid >> 6;
    if ((tid & 63) == 0) red[wv] = mx;
    __syncthreads();
    mx = fmaxf(fmaxf(red[0], red[1]), fmaxf(red[2], red[3]));
    float s = 0.0f;
#pragma unroll
    for (int i = 0; i < 4; ++i) {
        s += __expf(v[i].x - mx) + __expf(v[i].y - mx) + __expf(v[i].z - mx) + __expf(v[i].w - mx);
    }
#pragma unroll
    for (int o = 32; o >= 1; o >>= 1) s += __shfl_xor(s, o);
    if ((tid & 63) == 0) red[4 + wv] = s;
    __syncthreads();
    if (tid == 0) {
        rowmax[row] = mx;
        rowinv[row] = 1.0f / (red[4] + red[5] + red[6] + red[7]);
    }
}

// ---------------- kernel A2: W^T[k][m] = softmax weight, tiled transpose ----------------
__global__ __launch_bounds__(256) void kT(const float* __restrict__ sel,
                                          const float* __restrict__ rowmax,
                                          const float* __restrict__ rowinv,
                                          float* __restrict__ WT)
{
    __shared__ float tile[64][65];
    __shared__ float smx[64], sinv[64];
    const int t = threadIdx.x;
    const int k0 = blockIdx.x * 64;
    const int m0 = blockIdx.y * 64;

    if (t < 64) { smx[t] = rowmax[m0 + t]; sinv[t] = rowinv[m0 + t]; }
    __syncthreads();

    const int m_l = t >> 4;
    const int k_l4 = (t & 15) << 2;
#pragma unroll
    for (int i = 0; i < 4; ++i) {
        const int ml = m_l + (i << 4);
        const float mxv = smx[ml], invv = sinv[ml];
        float4 v = *(const float4*)(sel + (size_t)(m0 + ml) * 4096 + k0 + k_l4);
        tile[k_l4 + 0][ml] = __expf(v.x - mxv) * invv;
        tile[k_l4 + 1][ml] = __expf(v.y - mxv) * invv;
        tile[k_l4 + 2][ml] = __expf(v.z - mxv) * invv;
        tile[k_l4 + 3][ml] = __expf(v.w - mxv) * invv;
    }
    __syncthreads();

    const int k_l = t >> 2;
    const int mb = (t & 3) << 2;
#pragma unroll
    for (int i = 0; i < 4; ++i) {
        const int ml = mb + (i << 4);
        float4 w = make_float4(tile[k_l][ml], tile[k_l][ml+1], tile[k_l][ml+2], tile[k_l][ml+3]);
        *(float4*)(WT + (size_t)(k0 + k_l) * 1024 + m0 + ml) = w;
    }
}

// ---------------- kernel B: build per-column nonzero lists of items (deterministic) -----
__global__ __launch_bounds__(256) void kfill(const float* __restrict__ items,
                                             int* __restrict__ kidx,
                                             float* __restrict__ kval,
                                             int* __restrict__ ncol)
{
    const int c = blockIdx.x;
    const int t = threadIdx.x;
    const int wv = t >> 6;
    const int lane = t & 63;
    __shared__ int wcnt[4];

    const int kc0 = wv << 10;
    float vv[16];
    int cnt = 0;
#pragma unroll
    for (int it = 0; it < 16; ++it) {
        const int k = kc0 + (it << 6) + lane;
        const float v = items[(size_t)k * 514 + c];
        vv[it] = v;
        unsigned long long mb = __ballot(v != 0.0f);
        cnt += __popcll(mb);
    }
    if (lane == 0) wcnt[wv] = cnt;
    __syncthreads();

    int base = 0;
#pragma unroll
    for (int q = 0; q < 4; ++q) if (q < wv) base += wcnt[q];

    const unsigned long long ltmask = (lane == 63) ? 0x7fffffffffffffffull
                                                   : ((1ull << lane) - 1ull);
#pragma unroll
    for (int it = 0; it < 16; ++it) {
        const float v = vv[it];
        const bool nz = (v != 0.0f);
        unsigned long long mb = __ballot(nz);
        if (nz) {
            const int slot = base + __popcll(mb & ltmask);
            if (slot < CAP) {
                kidx[c * CAP + slot] = kc0 + (it << 6) + lane;
                kval[c * CAP + slot] = v;
            }
        }
        base += __popcll(mb);
    }
    if (t == 0) ncol[c] = wcnt[0] + wcnt[1] + wcnt[2] + wcnt[3];
}

// ---------------- kernel B2: sparse matmul + transform -> P4 (float4 {L,M,C,S} per bin) ----
// grid (4 mchunks, 514 c): same-c blocks dispatch-adjacent -> WT rows shared in L2/XCD.
__global__ __launch_bounds__(256) void kspmm(const float* __restrict__ WT,
                                             const int* __restrict__ kidx,
                                             const float* __restrict__ kval,
                                             const int* __restrict__ ncol,
                                             float2* __restrict__ P2)
{
    __shared__ int   ski[CAP];
    __shared__ float skv[CAP];
    const int c = blockIdx.y;
    const int m = (blockIdx.x << 8) + threadIdx.x;
    const int nn = min(ncol[c], CAP);
    if (threadIdx.x < nn) {
        ski[threadIdx.x] = kidx[c * CAP + threadIdx.x];
        skv[threadIdx.x] = kval[c * CAP + threadIdx.x];
    }
    __syncthreads();

    float acc = 0.0f;
    int i = 0;
    for (; i + 4 <= nn; i += 4) {
        const int k0 = ski[i], k1 = ski[i+1], k2 = ski[i+2], k3 = ski[i+3];
        const float v0 = skv[i], v1 = skv[i+1], v2 = skv[i+2], v3 = skv[i+3];
        const float w0 = WT[(size_t)k0 * 1024 + m];
        const float w1 = WT[(size_t)k1 * 1024 + m];
        const float w2 = WT[(size_t)k2 * 1024 + m];
        const float w3 = WT[(size_t)k3 * 1024 + m];
        acc = fmaf(v0, w0, acc);
        acc = fmaf(v1, w1, acc);
        acc = fmaf(v2, w2, acc);
        acc = fmaf(v3, w3, acc);
    }
    for (; i < nn; ++i) {
        acc = fmaf(skv[i], WT[(size_t)ski[i] * 1024 + m], acc);
    }

    const float x = acc;
    if (c < 257) {
        float mm = 0.9999f / (1.0f + __expf(-x));
        P2[((size_t)m * 257 + c) * 2] = make_float2(__log2f(mm), mm);
    } else {
        float e2 = __expf(2.0f * x);
        float th = (e2 - 1.0f) / (e2 + 1.0f);
        float ph = PI_F * th;
        float sn, cs;
        __sincosf(ph, &sn, &cs);
        P2[((size_t)m * 257 + (c - 257)) * 2 + 1] = make_float2(cs, sn);
    }
}

// ---------------- kernel C: 16 lanes per j-block, radix-16^2 IFFT, packed-f32 complex ----
// 256 cf2 slots per job (32KB/block -> 5 blocks/CU): bin-256 kept in regs (group-uniform),
// transpose uses XOR swizzle (gl<<4)|(n1^gl) — conflict-free without padding.
__global__ __launch_bounds__(256) void kres(const float4* __restrict__ P4, float* __restrict__ out)
{
    const int tid = threadIdx.x;
    const int lane = tid & 63;
    const int wv = tid >> 6;
    const int g = lane >> 4;
    const int gl = lane & 15;
    const int item = blockIdx.x >> 3;
    const int jg = blockIdx.x & 7;

    __shared__ cf2 U[16 * 256];
    cf2* ub = U + (wv * 4 + g) * 256;

    const int j = jg * 16 + wv * 4 + g;
    const float fj = (float)j;
    const float gf = (j > 0) ? 1.0f : 0.0f;
    const float sg = (gl & 1) ? -gf : gf;     // (-1)^c * gf, c = gl+16r

    const int pb4 = item * 257;

    // ---- phase 1: load bins, build S (regs) and V -> LDS
    cf2 S[16];
#pragma unroll
    for (int r = 0; r < 16; ++r) {
        float4 q = P4[pb4 + gl + 16*r];       // {L, M, C, S}
        float p = EXP2F(fj * q.x);
        cf2 F = p * mkc(q.z, q.w);
        cf2 Sv = (q.y + sg) * F;
        cf2 Vv = (q.y - sg) * F;
        if (gl == 0 && r == 0) { Sv.y = 0.0f; Vv.y = 0.0f; }  // DC imag dropped
        S[r] = Sv;
        ub[gl + 16*r] = Vv;
    }
    // bin 256 (group-uniform; computed by every lane, kept in registers)
    float4 q6 = P4[pb4 + 256];
    float pc6 = EXP2F(fj * q6.x) * q6.z;
    const float S6 = (q6.y + gf) * pc6;
    const float V6 = (q6.y - gf) * pc6;
    cfence();

    // ---- phase 2: Hann 3-tap, H into S regs
    float H6;
#pragma unroll
    for (int r = 0; r < 16; ++r) {
        const int c = gl + 16*r;
        const int im = (c == 0) ? 1 : c - 1;
        cf2 Vm = ub[im];
        if (c == 0) Vm.y = -Vm.y;             // hermitian V[-1] = conj V[1]
        cf2 Vp;
        if (r == 15) Vp = (gl == 15) ? mkc(V6, 0.0f) : ub[c + 1];
        else         Vp = ub[c + 1];
        S[r] = 0.5f * S[r] - 0.25f * (Vm + Vp);
    }
    H6 = 0.5f*S6 - 0.5f*ub[255].x;            // read before overwrite
    cfence();

    // write H over V (same-wave in-order)
#pragma unroll
    for (int r = 0; r < 16; ++r) ub[gl + 16*r] = S[r];
    cfence();

    // ---- phase 3: half-size packing -> Z (into S regs)
    cf2 zw0;
    {
        float s, c;
        __sincosf((6.283185307179586f/512.0f) * (float)gl, &s, &c);
        zw0 = mkc(c, s);
    }
    const float ZKC[16] = { 1.0f, 0.980785280403230f, 0.923879532511287f, 0.831469612302545f,
                            0.707106781186548f, 0.555570233019602f, 0.382683432365090f, 0.195090322016128f,
                            0.0f, -0.195090322016128f, -0.382683432365090f, -0.555570233019602f,
                            -0.707106781186548f, -0.831469612302545f, -0.923879532511287f, -0.980785280403230f };
    const float ZKS[16] = { 0.0f, 0.195090322016128f, 0.382683432365090f, 0.555570233019602f,
                            0.707106781186548f, 0.831469612302545f, 0.923879532511287f, 0.980785280403230f,
                            1.0f, 0.980785280403230f, 0.923879532511287f, 0.831469612302545f,
                            0.707106781186548f, 0.555570233019602f, 0.382683432365090f, 0.195090322016128f };
#pragma unroll
    for (int r = 0; r < 16; ++r) {
        const int c = gl + 16*r;
        cf2 Hk = S[r];
        cf2 cHm;
        if (r == 0) cHm = (gl == 0) ? mkc(H6, 0.0f) : cjg(ub[256 - c]);
        else        cHm = cjg(ub[256 - c]);
        cf2 w = cmulv(mkc(ZKC[r], ZKS[r]), zw0);
        cf2 A = Hk + cHm;
        cf2 B = Hk - cHm;
        S[r] = (A + cmulv(ci(w), B)) * (1.0f/512.0f);
    }
    cfence();   // all reads done before transpose writes (same buffer)

    // ---- FFT step 1: lane-local 16-pt IDFT over k2 (register axis); k1 = gl
    idft16_full(S);

    // ---- twiddle e^{2pi i k1 n1/256} + transpose write (XOR-swizzled, no pad)
    {
        cf2 wt = cmulv(zw0, zw0);             // e^{2pi i gl/256} = zw0^2
        cf2 ww = mkc(1.0f, 0.0f);
#pragma unroll
        for (int n1 = 0; n1 < 16; ++n1) {
            ub[(gl << 4) | (n1 ^ gl)] = cmulv(S[n1], ww);
            ww = cmulv(ww, wt);
        }
    }
    cfence();

    // ---- transpose read: lane gl becomes n1 = gl; T[k1]
    cf2 T[16];
#pragma unroll
    for (int k1 = 0; k1 < 16; ++k1) T[k1] = ub[(k1 << 4) | (gl ^ k1)];

    // ---- FFT step 2: lane-local 16-pt IDFT over k1, outputs n2 = 0..7 only
    idft16_low8(T);

    // ---- store: z[n1 + 16 n2] -> out cf2 slot (j<<7) + gl + 16*n2
    cf2* o2 = (cf2*)out + (size_t)item * 16384 + (j << 7);
#pragma unroll
    for (int n2 = 0; n2 < 8; ++n2) o2[gl + 16*n2] = T[n2];
}

extern "C" void kernel_launch(void* const* d_in, const int* in_sizes, int n_in,
                              void* d_out, int out_size, void* d_ws, size_t ws_size,
                              hipStream_t stream)
{
    const float* sel   = (const float*)d_in[0];   // (8,32,4,4096) f32 -> [1024][4096]
    const float* items = (const float*)d_in[1];   // (4096,514) f32
    float* out = (float*)d_out;                   // [1024][32768] f32
    float* ws  = (float*)d_ws;

    // Scratch in d_out (all dead before kres rewrites out):
    float* WT     = out;                          // 4096*1024 floats
    float* rowmax = out + 4194304;                // 1024
    float* rowinv = out + 4195328;                // 1024
    int*   ncol   = (int*)(out + 4196352);        // 514
    int*   kidx   = (int*)(out + 4196866);        // 514*CAP
    float* kval   = (float*)(out + 4196866 + 514*CAP);
    float4* P4    = (float4*)ws;                  // 1024*257 float4

    ksoft<<<1024, 256, 0, stream>>>(sel, rowmax, rowinv);
    kT<<<dim3(64, 16), 256, 0, stream>>>(sel, rowmax, rowinv, WT);
    kfill<<<514, 256, 0, stream>>>(items, kidx, kval, ncol);
    kspmm<<<dim3(4, 514), 256, 0, stream>>>(WT, kidx, kval, ncol, (float2*)ws);
    kres<<<8192, 256, 0, stream>>>(P4, out);
}